// Round 9
// baseline (306.304 us; speedup 1.0000x reference)
//
#include <hip/hip_runtime.h>
#include <hip/hip_cooperative_groups.h>
#include <math.h>

namespace cg = cooperative_groups;

typedef unsigned short u16;
typedef __attribute__((ext_vector_type(8))) short bf16x8;
typedef __attribute__((ext_vector_type(4))) float f32x4;

#define BB 2
#define NN 512
#define SCALEF 0.17677669529663687f  // 1/sqrt(16 + 4*4)

__device__ __forceinline__ u16 f2bf(float x) {
  union { float f; unsigned u; } c; c.f = x;
  unsigned r = (c.u + 0x7FFFu + ((c.u >> 16) & 1u)) >> 16;
  return (u16)r;
}
__device__ __forceinline__ float bf2f(u16 h) {
  union { unsigned u; float f; } c; c.u = ((unsigned)h) << 16;
  return c.f;
}

// ====== direct-global MFMA tile: one wave, MR*16 rows x NF*16 cols ======
template<int MR, int NF>
__device__ __forceinline__ void mfma_tile(
    const u16* __restrict__ Ah, const u16* __restrict__ Al, int lda,
    const u16* __restrict__ Bh, const u16* __restrict__ Bl, int ldb,
    int kBeg, int kEnd, int arow, int bcol, f32x4 (&acc)[MR][NF]) {
  const int lane = threadIdx.x & 63;
  const int rr = lane & 15, kg = lane >> 4;
  const u16* pah = Ah + (size_t)(arow + rr) * lda + kg * 8;
  const u16* pal = Al + (size_t)(arow + rr) * lda + kg * 8;
  const u16* pbh = Bh + (size_t)(bcol + rr) * ldb + kg * 8;
  const u16* pbl = Bl + (size_t)(bcol + rr) * ldb + kg * 8;
#pragma unroll 2
  for (int k0 = kBeg; k0 < kEnd; k0 += 32) {
    bf16x8 a_h[MR], a_l[MR], b_h[NF], b_l[NF];
#pragma unroll
    for (int m = 0; m < MR; ++m) {
      a_h[m] = *(const bf16x8*)(pah + (size_t)m * 16 * lda + k0);
      a_l[m] = *(const bf16x8*)(pal + (size_t)m * 16 * lda + k0);
    }
#pragma unroll
    for (int f = 0; f < NF; ++f) {
      b_h[f] = *(const bf16x8*)(pbh + (size_t)f * 16 * ldb + k0);
      b_l[f] = *(const bf16x8*)(pbl + (size_t)f * 16 * ldb + k0);
    }
#pragma unroll
    for (int m = 0; m < MR; ++m)
#pragma unroll
      for (int f = 0; f < NF; ++f) {
        acc[m][f] = __builtin_amdgcn_mfma_f32_16x16x32_bf16(a_h[m], b_h[f], acc[m][f], 0, 0, 0);
        acc[m][f] = __builtin_amdgcn_mfma_f32_16x16x32_bf16(a_h[m], b_l[f], acc[m][f], 0, 0, 0);
        acc[m][f] = __builtin_amdgcn_mfma_f32_16x16x32_bf16(a_l[m], b_h[f], acc[m][f], 0, 0, 0);
      }
  }
}

struct MegaArgs {
  const float *hidden, *xyz;
  const float *W_qk, *b_qk, *W_vs, *b_vs, *W_so, *b_so, *W_pqk, *b_pqk;
  const float *W_pv, *b_pv, *W_po, *b_po, *W_fp, *b_fp;
  u16 *Hhi, *Hlo, *WINh, *WINl, *WOPh, *WOPl, *WFPh, *WFPl;
  u16 *QKh, *QKl, *VVh, *VVl, *SRh, *SRl, *PRh, *PRl;
  float *QPf, *ATTf;
  u16 *VTh, *VTl;
  float *out_res, *out_xyz;
};

#define SMEM_BYTES 66816

__global__ __launch_bounds__(256) void mega(MegaArgs A) {
  __shared__ __align__(16) char smem[SMEM_BYTES];
  const int bid = blockIdx.x, tid = threadIdx.x;
  cg::grid_group grid = cg::this_grid();

  // ================= stage 0: prep (weights transpose+split, hidden split, xyz init) =================
  for (int it = bid; it < 917; it += 256) {
    if (it < 852) {
      const float* src; u16 *dh, *dl;
      int Ns, dld, nOff, kOff, tn, lt;
      if (it < 144)      { src = A.W_qk;  Ns = 384; dh = A.WINh; dl = A.WINl; dld = 384; nOff = 0;   kOff = 0;   tn = 12; lt = it; }
      else if (it < 216) { src = A.W_vs;  Ns = 192; dh = A.WINh; dl = A.WINl; dld = 384; nOff = 384; kOff = 0;   tn = 6;  lt = it - 144; }
      else if (it < 324) { src = A.W_pv;  Ns = 288; dh = A.WINh; dl = A.WINl; dld = 384; nOff = 576; kOff = 0;   tn = 9;  lt = it - 216; }
      else if (it < 384) { src = A.W_pqk; Ns = 144; dh = A.WINh; dl = A.WINl; dld = 384; nOff = 864; kOff = 0;   tn = 5;  lt = it - 324; }
      else if (it < 456) { src = A.W_so;  Ns = 384; dh = A.WOPh; dl = A.WOPl; dld = 480; nOff = 0;   kOff = 0;   tn = 12; lt = it - 384; }
      else if (it < 564) { src = A.W_po;  Ns = 384; dh = A.WOPh; dl = A.WOPl; dld = 480; nOff = 384; kOff = 192; tn = 12; lt = it - 456; }
      else               { src = A.W_fp;  Ns = 384; dh = A.WFPh; dl = A.WFPl; dld = 768; nOff = 0;   kOff = 0;   tn = 12; lt = it - 564; }
      int k0 = (lt / tn) * 32, n0 = (lt % tn) * 32;
      float (*T)[33] = (float (*)[33])smem;
      int ty = tid >> 5, tx = tid & 31;
      for (int r = ty; r < 32; r += 8) {
        int gn = n0 + tx;
        T[r][tx] = (gn < Ns) ? src[(size_t)(k0 + r) * Ns + gn] : 0.f;
      }
      __syncthreads();
      for (int r = ty; r < 32; r += 8) {
        int gn = n0 + r;
        if (gn < Ns) {
          float v = T[tx][r];
          u16 hi = f2bf(v), lo = f2bf(v - bf2f(hi));
          size_t idx = (size_t)(nOff + gn) * dld + kOff + k0 + tx;
          dh[idx] = hi; dl[idx] = lo;
        }
      }
      __syncthreads();
    } else if (it < 916) {
      int base = (it - 852) * 1536;
      for (int u = tid; u < 1536; u += 256) {
        float4 v = ((const float4*)A.hidden)[base + u];
        u16 h0 = f2bf(v.x), h1 = f2bf(v.y), h2 = f2bf(v.z), h3 = f2bf(v.w);
        u16 l0 = f2bf(v.x - bf2f(h0)), l1 = f2bf(v.y - bf2f(h1));
        u16 l2 = f2bf(v.z - bf2f(h2)), l3 = f2bf(v.w - bf2f(h3));
        ((ushort4*)A.Hhi)[base + u] = make_ushort4(h0, h1, h2, h3);
        ((ushort4*)A.Hlo)[base + u] = make_ushort4(l0, l1, l2, l3);
      }
    } else {
#pragma unroll
      for (int e = 0; e < 3; ++e) {
        int idx = tid + 256 * e;
        ((float4*)A.out_xyz)[idx] = ((const float4*)A.xyz)[idx];
      }
    }
  }
  grid.sync();

  // ================= stage 1: input projections (168 items x 4 waves) =================
  for (int it = bid; it < 168; it += 256) {
    int ir = it / 21, ic = it - ir * 21;
    const int w = tid >> 6, lane = tid & 63;
    int row0 = ir * 128 + w * 32, col0 = ic * 48;
    f32x4 acc[2][3] = {};
    mfma_tile<2, 3>(A.Hhi, A.Hlo, 384, A.WINh, A.WINl, 384, 0, 384, row0, col0, acc);
    int rb = (lane >> 4) << 2, cc = lane & 15;
#pragma unroll
    for (int f = 0; f < 3; ++f) {
      int n0 = col0 + f * 16, n = n0 + cc;
      float bias = (n0 < 384) ? A.b_qk[n]
                 : (n0 < 576) ? A.b_vs[n - 384]
                 : (n0 < 864) ? A.b_pv[n - 576] : A.b_pqk[n - 864];
#pragma unroll
      for (int m = 0; m < 2; ++m)
#pragma unroll
        for (int r = 0; r < 4; ++r) {
          float v = acc[m][f][r] + bias;
          int row = row0 + m * 16 + rb + r;
          if (n0 < 384) {
            u16 hi = f2bf(v);
            A.QKh[(size_t)row * 384 + n] = hi;
            A.QKl[(size_t)row * 384 + n] = f2bf(v - bf2f(hi));
          } else if (n0 < 864) {
            int c = n - 384;
            u16 hi = f2bf(v);
            A.VVh[(size_t)row * 480 + c] = hi;
            A.VVl[(size_t)row * 480 + c] = f2bf(v - bf2f(hi));
          } else {
            A.QPf[(size_t)row * 144 + (n - 864)] = v;
          }
        }
    }
  }
  grid.sync();

  // ================= stage 2: attn logits (272 items) + V transpose (480 items) =================
  for (int it = bid; it < 752; it += 256) {
    if (it < 272) {
      const int b = it / 136;
      int tt = it - b * 136, ti_ = 0;
      while (tt >= 16 - ti_) { tt -= 16 - ti_; ++ti_; }
      const int tj_ = ti_ + tt;
      const int i0 = ti_ * 32, j0 = tj_ * 32;
      const bool offdiag = (tj_ != ti_);
      float (*Pi)[244] = (float (*)[244])smem;                 // 31232 B
      float (*Pj)[244] = (float (*)[244])(smem + 31232);       // 31232 B
      float* Sf = (float*)(smem + 62464);                      // 4224 B
      for (int u = tid; u < 3072; u += 256) {
        int side = (u >= 1536) ? 1 : 0;
        int rem = u - side * 1536;
        int row = rem / 48, hp = rem - row * 48;
        int grow = b * NN + (side ? j0 : i0) + row;
        const float* p = A.QPf + (size_t)grow * 144 + hp * 3;
        float x = p[0], y = p[1], z = p[2];
        float n2 = x * x + y * y + z * z;
        float inv = __frsqrt_rn(n2 + 1e-12f);
        float* dst = side ? &Pj[row][0] : &Pi[row][0];
        ((float4*)dst)[hp] = make_float4(x, y, z, n2);
        dst[192 + hp] = inv;
      }
      __syncthreads();
      const int tj = tid & 15, ti = tid >> 4;
      float a00 = 0.f, a01 = 0.f, a10 = 0.f, a11 = 0.f;
      {
        const float4* A0 = (const float4*)&Pi[ti][0];
        const float4* A1 = (const float4*)&Pi[ti + 16][0];
        const float4* B0 = (const float4*)&Pj[tj][0];
        const float4* B1 = (const float4*)&Pj[tj + 16][0];
        const float* iA0 = &Pi[ti][192];
        const float* iA1 = &Pi[ti + 16][192];
        const float* iB0 = &Pj[tj][192];
        const float* iB1 = &Pj[tj + 16][192];
#pragma unroll 4
        for (int hp = 0; hp < 48; ++hp) {
          float4 p0 = A0[hp], p1 = A1[hp], q0 = B0[hp], q1 = B1[hp];
          float va0 = iA0[hp], va1 = iA1[hp], vb0 = iB0[hp], vb1 = iB1[hp];
          {
            float dot = p0.x * q0.x + p0.y * q0.y + p0.z * q0.z;
            float d2 = fmaxf(fmaf(-2.f, dot, p0.w + q0.w), 0.f) + 1e-12f;
            a00 += d2 * __frsqrt_rn(d2) + dot * (va0 * vb0);
          }
          {
            float dot = p0.x * q1.x + p0.y * q1.y + p0.z * q1.z;
            float d2 = fmaxf(fmaf(-2.f, dot, p0.w + q1.w), 0.f) + 1e-12f;
            a01 += d2 * __frsqrt_rn(d2) + dot * (va0 * vb1);
          }
          {
            float dot = p1.x * q0.x + p1.y * q0.y + p1.z * q0.z;
            float d2 = fmaxf(fmaf(-2.f, dot, p1.w + q0.w), 0.f) + 1e-12f;
            a10 += d2 * __frsqrt_rn(d2) + dot * (va1 * vb0);
          }
          {
            float dot = p1.x * q1.x + p1.y * q1.y + p1.z * q1.z;
            float d2 = fmaxf(fmaf(-2.f, dot, p1.w + q1.w), 0.f) + 1e-12f;
            a11 += d2 * __frsqrt_rn(d2) + dot * (va1 * vb1);
          }
        }
      }
      Sf[ti * 33 + tj] = a00;
      Sf[ti * 33 + tj + 16] = a01;
      Sf[(ti + 16) * 33 + tj] = a10;
      Sf[(ti + 16) * 33 + tj + 16] = a11;
      f32x4 qij[1][1] = {}, qji[1][1] = {};
      const int w = tid >> 6, lane = tid & 63;
      {
        int arow = b * NN + i0 + (w >> 1) * 16;
        int brow = b * NN + j0 + (w & 1) * 16;
        mfma_tile<1, 1>(A.QKh, A.QKl, 384, A.QKh + 192, A.QKl + 192, 384, 0, 192, arow, brow, qij);
        if (offdiag) {
          int arow2 = b * NN + j0 + (w >> 1) * 16;
          int brow2 = b * NN + i0 + (w & 1) * 16;
          mfma_tile<1, 1>(A.QKh, A.QKl, 384, A.QKh + 192, A.QKl + 192, 384, 0, 192, arow2, brow2, qji);
        }
      }
      __syncthreads();
      const int rl = (w >> 1) * 16 + ((lane >> 4) << 2);
      const int cl = (w & 1) * 16 + (lane & 15);
      float* Cb = A.ATTf + (size_t)b * NN * NN;
#pragma unroll
      for (int r = 0; r < 4; ++r)
        Cb[(size_t)(i0 + rl + r) * NN + j0 + cl] = qij[0][0][r] + Sf[(rl + r) * 33 + cl];
      if (offdiag) {
#pragma unroll
        for (int r = 0; r < 4; ++r)
          Cb[(size_t)(j0 + rl + r) * NN + i0 + cl] = qji[0][0][r] + Sf[cl * 33 + rl + r];
      }
      __syncthreads();
    } else {
      int tv = it - 272;                   // 480 tiles = 2 x 16 x 15
      int b = tv / 240, rem = tv - b * 240;
      int bx = rem % 15, by = rem / 15;
      u16 (*Th)[34] = (u16 (*)[34])smem;           // 2176 B
      u16 (*Tl)[34] = (u16 (*)[34])(smem + 2176);  // 2176 B
      int ty = tid >> 5, tx = tid & 31;
      for (int r = ty; r < 32; r += 8) {
        size_t src = (size_t)(b * NN + by * 32 + r) * 480 + bx * 32 + tx;
        Th[r][tx] = A.VVh[src];
        Tl[r][tx] = A.VVl[src];
      }
      __syncthreads();
      for (int r = ty; r < 32; r += 8) {
        size_t dst = (size_t)b * 480 * NN + (size_t)(bx * 32 + r) * NN + by * 32 + tx;
        A.VTh[dst] = Th[tx][r];
        A.VTl[dst] = Tl[tx][r];
      }
      __syncthreads();
    }
  }
  grid.sync();

  // ================= stage 3: row softmax, in-place f32 -> bf16 hi/lo =================
  for (int it = bid; it < 1024; it += 256) {
    float* p = A.ATTf + (size_t)it * NN;
    float v0 = p[tid] * SCALEF, v1 = p[tid + 256] * SCALEF;
    float* red = (float*)smem;
    red[tid] = fmaxf(v0, v1);
    __syncthreads();
    for (int s = 128; s > 0; s >>= 1) {
      if (tid < s) red[tid] = fmaxf(red[tid], red[tid + s]);
      __syncthreads();
    }
    float m = red[0];
    __syncthreads();
    float e0 = __expf(v0 - m), e1 = __expf(v1 - m);
    red[tid] = e0 + e1;
    __syncthreads();
    for (int s = 128; s > 0; s >>= 1) {
      if (tid < s) red[tid] += red[tid + s];
      __syncthreads();
    }
    float inv = 1.0f / red[0];
    __syncthreads();
    float w0 = e0 * inv, w1 = e1 * inv;
    u16 h0 = f2bf(w0), h1 = f2bf(w1);
    u16* q = (u16*)p;
    q[tid] = h0;
    q[tid + 256] = h1;
    q[512 + tid] = f2bf(w0 - bf2f(h0));
    q[512 + tid + 256] = f2bf(w1 - bf2f(h1));
  }
  grid.sync();

  // ================= stage 4: PV GEMM (80 items x 4 waves, barrier-free) =================
  for (int it = bid; it < 80; it += 256) {
    int b = it / 40, rem = it - b * 40;
    int ir = rem / 10, ic = rem - ir * 10;
    const int w = tid >> 6, lane = tid & 63;
    int row0 = ir * 128 + w * 32, col0 = ic * 48;
    f32x4 acc[2][3] = {};
    const u16* P = (const u16*)A.ATTf + (size_t)b * NN * 1024;
    mfma_tile<2, 3>(P, P + 512, 1024,
                    A.VTh + (size_t)b * 480 * NN, A.VTl + (size_t)b * 480 * NN, NN,
                    0, NN, row0, col0, acc);
    const int rb = (lane >> 4) << 2, cc = lane & 15;
    u16* oh = A.SRh + (size_t)b * NN * 480;
    u16* ol = A.SRl + (size_t)b * NN * 480;
#pragma unroll
    for (int m = 0; m < 2; ++m)
#pragma unroll
      for (int f = 0; f < 3; ++f) {
        int n = col0 + f * 16 + cc;
#pragma unroll
        for (int r = 0; r < 4; ++r) {
          float v = acc[m][f][r];
          u16 hi = f2bf(v);
          ol[(size_t)(row0 + m * 16 + rb + r) * 480 + n] = f2bf(v - bf2f(hi));
          oh[(size_t)(row0 + m * 16 + rb + r) * 480 + n] = hi;
        }
      }
  }
  grid.sync();

  // ================= stage 5: output projections + delta_xyz (128 items x 4 waves) =================
  for (int it = bid; it < 128; it += 256) {
    int ir = it >> 4, t = it & 15;
    const int w = tid >> 6, lane = tid & 63;
    int row0 = ir * 128 + w * 32, col0 = t * 48;
    const int kBeg = (t < 8) ? 0 : 192, kEnd = (t < 8) ? 192 : 480;
    f32x4 acc[2][3] = {};
    mfma_tile<2, 3>(A.SRh, A.SRl, 480, A.WOPh, A.WOPl, 480, kBeg, kEnd, row0, col0, acc);
    float (*D)[49] = (float (*)[49])(smem + w * 6272);
    const int rb = (lane >> 4) << 2, cc = lane & 15;
#pragma unroll
    for (int m = 0; m < 2; ++m)
#pragma unroll
      for (int f = 0; f < 3; ++f) {
        int n = col0 + f * 16 + cc;
        float bias = (n < 384) ? A.b_so[n] : A.b_po[n - 384];
#pragma unroll
        for (int r = 0; r < 4; ++r) {
          float v = acc[m][f][r] + bias;
          u16 hi = f2bf(v);
          A.PRh[(size_t)(row0 + m * 16 + rb + r) * 768 + n] = hi;
          A.PRl[(size_t)(row0 + m * 16 + rb + r) * 768 + n] = f2bf(v - bf2f(hi));
          if (t >= 8) D[m * 16 + rb + r][f * 16 + cc] = v;
        }
      }
    if (t >= 8) {
      __syncthreads();
      if (lane < 32) {
        float sx = 0.f, sy = 0.f, sz = 0.f;
#pragma unroll
        for (int p = 0; p < 16; ++p) {
          sx += D[lane][3 * p];
          sy += D[lane][3 * p + 1];
          sz += D[lane][3 * p + 2];
        }
        int token = row0 + lane;
        atomicAdd(A.out_xyz + (size_t)token * 3 + 0, sx * (1.0f / 128.f));
        atomicAdd(A.out_xyz + (size_t)token * 3 + 1, sy * (1.0f / 128.f));
        atomicAdd(A.out_xyz + (size_t)token * 3 + 2, sz * (1.0f / 128.f));
      }
      __syncthreads();
    }
  }
  grid.sync();

  // ================= stage 6: final GEMM, K-split x2 with LDS combine (128 items) =================
  for (int it = bid; it < 128; it += 256) {
    const int half = tid >> 7;                  // two 2-wave units per block
    const int unit = it * 2 + half;             // 256 units
    const int rs = unit >> 3, c = unit & 7;
    const int row0 = rs * 32, col0 = c * 48;
    const int wk = (tid >> 6) & 1, lane = tid & 63;
    f32x4 acc[2][3] = {};
    mfma_tile<2, 3>(A.PRh, A.PRl, 768, A.WFPh, A.WFPl, 768, wk * 384, wk * 384 + 384,
                    row0, col0, acc);
    float (*S)[52] = (float (*)[52])(smem + half * 6656);
    const int rb = (lane >> 4) << 2, cc = lane & 15;
    if (wk == 1) {
#pragma unroll
      for (int m = 0; m < 2; ++m)
#pragma unroll
        for (int f = 0; f < 3; ++f)
#pragma unroll
          for (int r = 0; r < 4; ++r)
            S[m * 16 + rb + r][f * 16 + cc] = acc[m][f][r];
    }
    __syncthreads();
    if (wk == 0) {
#pragma unroll
      for (int m = 0; m < 2; ++m)
#pragma unroll
        for (int f = 0; f < 3; ++f) {
          int n = col0 + f * 16 + cc;
#pragma unroll
          for (int r = 0; r < 4; ++r)
            A.out_res[(size_t)(row0 + m * 16 + rb + r) * 384 + n] =
                acc[m][f][r] + S[m * 16 + rb + r][f * 16 + cc] + A.b_fp[n];
        }
    }
    __syncthreads();
  }
}

extern "C" void kernel_launch(void* const* d_in, const int* in_sizes, int n_in,
                              void* d_out, int out_size, void* d_ws, size_t ws_size,
                              hipStream_t stream) {
  MegaArgs A;
  A.hidden = (const float*)d_in[0];
  A.xyz   = (const float*)d_in[1];
  A.W_qk  = (const float*)d_in[2];
  A.b_qk  = (const float*)d_in[3];
  A.W_vs  = (const float*)d_in[4];
  A.b_vs  = (const float*)d_in[5];
  A.W_so  = (const float*)d_in[6];
  A.b_so  = (const float*)d_in[7];
  A.W_pqk = (const float*)d_in[8];
  A.b_pqk = (const float*)d_in[9];
  A.W_pv  = (const float*)d_in[10];
  A.b_pv  = (const float*)d_in[11];
  A.W_po  = (const float*)d_in[12];
  A.b_po  = (const float*)d_in[13];
  A.W_fp  = (const float*)d_in[14];
  A.b_fp  = (const float*)d_in[15];

  A.out_res = (float*)d_out;                       // [B,N,384]
  A.out_xyz = A.out_res + (size_t)BB * NN * 384;   // [B,N,3]

  u16* p   = (u16*)d_ws;
  A.Hhi  = p;              p += 393216;
  A.Hlo  = p;              p += 393216;
  A.WINh = p;              p += 387072;
  A.WINl = p;              p += 387072;
  A.WOPh = p;              p += 368640;
  A.WOPl = p;              p += 368640;
  A.WFPh = p;              p += 294912;
  A.WFPl = p;              p += 294912;
  A.QKh  = p;              p += 393216;
  A.QKl  = p;              p += 393216;
  A.VVh  = p;              p += 491520;
  A.VVl  = p;              p += 491520;
  A.SRh  = p;              p += 491520;
  A.SRl  = p;              p += 491520;
  A.PRh  = p;              p += 786432;
  A.PRl  = p;              p += 786432;
  A.QPf  = (float*)p;      p += 2 * 147456;        // 147456 f32
  A.ATTf = (float*)p;                              // 524288 f32
  // VT overlays Hhi/Hlo/WINh (dead after stage 1; written in stage 2 after grid sync)
  A.VTh  = A.Hhi;
  A.VTl  = A.Hhi + 491520;

  void* kargs[] = { (void*)&A };
  hipLaunchCooperativeKernel((const void*)mega, dim3(256), dim3(256), kargs, 0, stream);
}

// Round 10
// 101.663 us; speedup vs baseline: 3.0129x; 3.0129x over previous
//
#include <hip/hip_runtime.h>
#include <math.h>

typedef unsigned short u16;
typedef __attribute__((ext_vector_type(8))) short bf16x8;
typedef __attribute__((ext_vector_type(4))) float f32x4;

#define BB 2
#define NN 512
#define SCALEF 0.17677669529663687f  // 1/sqrt(16 + 4*4)

__device__ __forceinline__ u16 f2bf(float x) {
  union { float f; unsigned u; } c; c.f = x;
  unsigned r = (c.u + 0x7FFFu + ((c.u >> 16) & 1u)) >> 16;
  return (u16)r;
}
__device__ __forceinline__ float bf2f(u16 h) {
  union { unsigned u; float f; } c; c.u = ((unsigned)h) << 16;
  return c.f;
}
__device__ __forceinline__ void pack8(const float* v, bf16x8& h, bf16x8& l) {
#pragma unroll
  for (int j = 0; j < 8; ++j) {
    u16 hi = f2bf(v[j]);
    h[j] = (short)hi;
    l[j] = (short)f2bf(v[j] - bf2f(hi));
  }
}
#define MFMA3(ACC, AH, AL, BH, BL)                                              \
  ACC = __builtin_amdgcn_mfma_f32_16x16x32_bf16(AH, BH, ACC, 0, 0, 0);          \
  ACC = __builtin_amdgcn_mfma_f32_16x16x32_bf16(AH, BL, ACC, 0, 0, 0);          \
  ACC = __builtin_amdgcn_mfma_f32_16x16x32_bf16(AL, BH, ACC, 0, 0, 0);

// ====== bf16 direct-global MFMA tile (A,B both bf16 hi/lo, NT) ======
template<int MR, int NF>
__device__ __forceinline__ void mfma_tile(
    const u16* __restrict__ Ah, const u16* __restrict__ Al, int lda,
    const u16* __restrict__ Bh, const u16* __restrict__ Bl, int ldb,
    int kBeg, int kEnd, int arow, int bcol, f32x4 (&acc)[MR][NF]) {
  const int lane = threadIdx.x & 63;
  const int rr = lane & 15, kg = lane >> 4;
  const u16* pah = Ah + (size_t)(arow + rr) * lda + kg * 8;
  const u16* pal = Al + (size_t)(arow + rr) * lda + kg * 8;
  const u16* pbh = Bh + (size_t)(bcol + rr) * ldb + kg * 8;
  const u16* pbl = Bl + (size_t)(bcol + rr) * ldb + kg * 8;
#pragma unroll 2
  for (int k0 = kBeg; k0 < kEnd; k0 += 32) {
    bf16x8 a_h[MR], a_l[MR], b_h[NF], b_l[NF];
#pragma unroll
    for (int m = 0; m < MR; ++m) {
      a_h[m] = *(const bf16x8*)(pah + (size_t)m * 16 * lda + k0);
      a_l[m] = *(const bf16x8*)(pal + (size_t)m * 16 * lda + k0);
    }
#pragma unroll
    for (int f = 0; f < NF; ++f) {
      b_h[f] = *(const bf16x8*)(pbh + (size_t)f * 16 * ldb + k0);
      b_l[f] = *(const bf16x8*)(pbl + (size_t)f * 16 * ldb + k0);
    }
#pragma unroll
    for (int m = 0; m < MR; ++m)
#pragma unroll
      for (int f = 0; f < NF; ++f) { MFMA3(acc[m][f], a_h[m], a_l[m], b_h[f], b_l[f]) }
  }
}

// ---------------- k_input: hidden(f32) @ W^T(f32 cols) -> QK | VT | QP ----------------
__global__ __launch_bounds__(64) void k_input(
    const float* __restrict__ hidden, const float* __restrict__ xyz,
    const float* __restrict__ W_qk, const float* __restrict__ b_qk,
    const float* __restrict__ W_vs, const float* __restrict__ b_vs,
    const float* __restrict__ W_pv, const float* __restrict__ b_pv,
    const float* __restrict__ W_pqk, const float* __restrict__ b_pqk,
    u16* __restrict__ QKh, u16* __restrict__ QKl,
    u16* __restrict__ VTh, u16* __restrict__ VTl,
    float* __restrict__ QPf, float* __restrict__ out_xyz) {
  __shared__ u16 Dh[48][32], Dl[48][32];
  const int lane = threadIdx.x;
  const int rr = lane & 15, kg = lane >> 4;
  const int row0 = blockIdx.y * 32, col0 = blockIdx.x * 48;
  const float* W; const float* bias; int Ns, region;
  if (col0 < 384)      { W = W_qk;  Ns = 384; bias = b_qk + col0;         W += col0;       region = 0; }
  else if (col0 < 576) { W = W_vs;  Ns = 192; bias = b_vs + (col0 - 384); W += col0 - 384; region = 1; }
  else if (col0 < 864) { W = W_pv;  Ns = 288; bias = b_pv + (col0 - 576); W += col0 - 576; region = 1; }
  else                 { W = W_pqk; Ns = 144; bias = b_pqk + (col0 - 864);W += col0 - 864; region = 2; }

  f32x4 acc[2][3] = {};
  const float* pa = hidden + (size_t)(row0 + rr) * 384 + kg * 8;
  const float* pw = W + rr;
  for (int k0 = 0; k0 < 384; k0 += 32) {
    bf16x8 a_h[2], a_l[2], b_h[3], b_l[3];
#pragma unroll
    for (int m = 0; m < 2; ++m) {
      float v[8];
      *(float4*)&v[0] = *(const float4*)(pa + (size_t)m * 16 * 384 + k0);
      *(float4*)&v[4] = *(const float4*)(pa + (size_t)m * 16 * 384 + k0 + 4);
      pack8(v, a_h[m], a_l[m]);
    }
    const float* bp0 = pw + (size_t)(k0 + kg * 8) * Ns;
#pragma unroll
    for (int f = 0; f < 3; ++f) {
      float v[8];
#pragma unroll
      for (int j = 0; j < 8; ++j) v[j] = bp0[(size_t)j * Ns + f * 16];
      pack8(v, b_h[f], b_l[f]);
    }
#pragma unroll
    for (int m = 0; m < 2; ++m)
#pragma unroll
      for (int f = 0; f < 3; ++f) { MFMA3(acc[m][f], a_h[m], a_l[m], b_h[f], b_l[f]) }
  }
  const int rb = (lane >> 4) << 2, cc = lane & 15;
  if (region == 0) {
#pragma unroll
    for (int f = 0; f < 3; ++f) {
      int n = col0 + f * 16 + cc;
      float bv = bias[f * 16 + cc];
#pragma unroll
      for (int m = 0; m < 2; ++m)
#pragma unroll
        for (int r = 0; r < 4; ++r) {
          float v = acc[m][f][r] + bv;
          int row = row0 + m * 16 + rb + r;
          u16 hi = f2bf(v);
          QKh[(size_t)row * 384 + n] = hi;
          QKl[(size_t)row * 384 + n] = f2bf(v - bf2f(hi));
        }
    }
  } else if (region == 2) {
#pragma unroll
    for (int f = 0; f < 3; ++f) {
      int c = (col0 - 864) + f * 16 + cc;
      float bv = bias[f * 16 + cc];
#pragma unroll
      for (int m = 0; m < 2; ++m)
#pragma unroll
        for (int r = 0; r < 4; ++r)
          QPf[(size_t)(row0 + m * 16 + rb + r) * 144 + c] = acc[m][f][r] + bv;
    }
  } else {
    // V region: transpose in LDS, write VT[b][c][token] bf16 hi/lo
#pragma unroll
    for (int f = 0; f < 3; ++f) {
      float bv = bias[f * 16 + cc];
#pragma unroll
      for (int m = 0; m < 2; ++m)
#pragma unroll
        for (int r = 0; r < 4; ++r) {
          float v = acc[m][f][r] + bv;
          u16 hi = f2bf(v);
          Dh[f * 16 + cc][m * 16 + rb + r] = hi;
          Dl[f * 16 + cc][m * 16 + rb + r] = f2bf(v - bf2f(hi));
        }
    }
    __syncthreads();
    const int b = row0 >> 9, rl = row0 & 511;
    const int cbase = col0 - 384;
    u16* dsth = VTh + (size_t)b * 480 * 512;
    u16* dstl = VTl + (size_t)b * 480 * 512;
    for (int u = lane; u < 192; u += 64) {
      int c = u >> 2, seg = u & 3;
      *(uint4*)(dsth + (size_t)(cbase + c) * 512 + rl + seg * 8) = *(const uint4*)&Dh[c][seg * 8];
      *(uint4*)(dstl + (size_t)(cbase + c) * 512 + rl + seg * 8) = *(const uint4*)&Dl[c][seg * 8];
    }
  }
  if (blockIdx.x == 18) {  // out_xyz init (once per 32 tokens)
    for (int t = lane; t < 96; t += 64)
      out_xyz[(size_t)row0 * 3 + t] = xyz[(size_t)row0 * 3 + t];
  }
}

// ---------------- k_attn: fused point term + scalar QK, symmetric tiles ----------------
#define PROW 244
__global__ __launch_bounds__(256) void k_attn(
    const u16* __restrict__ QKh, const u16* __restrict__ QKl,
    const float* __restrict__ QPf, float* __restrict__ ATTf) {
  __shared__ float Pi[32][PROW];
  __shared__ float Pj[32][PROW];
  __shared__ float Sf[32 * 33];
  const int b = blockIdx.z;
  int t = blockIdx.x, ti_ = 0;
  while (t >= 16 - ti_) { t -= 16 - ti_; ++ti_; }
  const int tj_ = ti_ + t;
  const int i0 = ti_ * 32, j0 = tj_ * 32;
  const bool offdiag = (tj_ != ti_);
  const int tid = threadIdx.x;
  for (int u = tid; u < 3072; u += 256) {
    int side = (u >= 1536) ? 1 : 0;
    int rem = u - side * 1536;
    int row = rem / 48, hp = rem - row * 48;
    int grow = b * NN + (side ? j0 : i0) + row;
    const float* p = QPf + (size_t)grow * 144 + hp * 3;
    float x = p[0], y = p[1], z = p[2];
    float n2 = x * x + y * y + z * z;
    float inv = __frsqrt_rn(n2 + 1e-12f);
    float* dst = side ? &Pj[row][0] : &Pi[row][0];
    ((float4*)dst)[hp] = make_float4(x, y, z, n2);
    dst[192 + hp] = inv;
  }
  __syncthreads();
  const int tj = tid & 15, ti = tid >> 4;
  float a00 = 0.f, a01 = 0.f, a10 = 0.f, a11 = 0.f;
  {
    const float4* A0 = (const float4*)&Pi[ti][0];
    const float4* A1 = (const float4*)&Pi[ti + 16][0];
    const float4* B0 = (const float4*)&Pj[tj][0];
    const float4* B1 = (const float4*)&Pj[tj + 16][0];
    const float* iA0 = &Pi[ti][192];
    const float* iA1 = &Pi[ti + 16][192];
    const float* iB0 = &Pj[tj][192];
    const float* iB1 = &Pj[tj + 16][192];
#pragma unroll 4
    for (int hp = 0; hp < 48; ++hp) {
      float4 p0 = A0[hp], p1 = A1[hp], q0 = B0[hp], q1 = B1[hp];
      float va0 = iA0[hp], va1 = iA1[hp], vb0 = iB0[hp], vb1 = iB1[hp];
      {
        float dot = p0.x * q0.x + p0.y * q0.y + p0.z * q0.z;
        float d2 = fmaxf(fmaf(-2.f, dot, p0.w + q0.w), 0.f) + 1e-12f;
        a00 += d2 * __frsqrt_rn(d2) + dot * (va0 * vb0);
      }
      {
        float dot = p0.x * q1.x + p0.y * q1.y + p0.z * q1.z;
        float d2 = fmaxf(fmaf(-2.f, dot, p0.w + q1.w), 0.f) + 1e-12f;
        a01 += d2 * __frsqrt_rn(d2) + dot * (va0 * vb1);
      }
      {
        float dot = p1.x * q0.x + p1.y * q0.y + p1.z * q0.z;
        float d2 = fmaxf(fmaf(-2.f, dot, p1.w + q0.w), 0.f) + 1e-12f;
        a10 += d2 * __frsqrt_rn(d2) + dot * (va1 * vb0);
      }
      {
        float dot = p1.x * q1.x + p1.y * q1.y + p1.z * q1.z;
        float d2 = fmaxf(fmaf(-2.f, dot, p1.w + q1.w), 0.f) + 1e-12f;
        a11 += d2 * __frsqrt_rn(d2) + dot * (va1 * vb1);
      }
    }
  }
  Sf[ti * 33 + tj] = a00;
  Sf[ti * 33 + tj + 16] = a01;
  Sf[(ti + 16) * 33 + tj] = a10;
  Sf[(ti + 16) * 33 + tj + 16] = a11;
  f32x4 qij[1][1] = {}, qji[1][1] = {};
  const int w = tid >> 6, lane = tid & 63;
  {
    int arow = b * NN + i0 + (w >> 1) * 16;
    int brow = b * NN + j0 + (w & 1) * 16;
    mfma_tile<1, 1>(QKh, QKl, 384, QKh + 192, QKl + 192, 384, 0, 192, arow, brow, qij);
    if (offdiag) {
      int arow2 = b * NN + j0 + (w >> 1) * 16;
      int brow2 = b * NN + i0 + (w & 1) * 16;
      mfma_tile<1, 1>(QKh, QKl, 384, QKh + 192, QKl + 192, 384, 0, 192, arow2, brow2, qji);
    }
  }
  __syncthreads();
  const int rl = (w >> 1) * 16 + ((lane >> 4) << 2);
  const int cl = (w & 1) * 16 + (lane & 15);
  float* Cb = ATTf + (size_t)b * NN * NN;
#pragma unroll
  for (int r = 0; r < 4; ++r)
    Cb[(size_t)(i0 + rl + r) * NN + j0 + cl] = qij[0][0][r] + Sf[(rl + r) * 33 + cl];
  if (offdiag) {
#pragma unroll
    for (int r = 0; r < 4; ++r)
      Cb[(size_t)(j0 + rl + r) * NN + i0 + cl] = qji[0][0][r] + Sf[cl * 33 + rl + r];
  }
}

// ---------------- k_pv: exp-in-register, deferred normalization, NT GEMM vs VT ----------------
__global__ __launch_bounds__(64) void k_pv(
    const float* __restrict__ ATTf,
    const u16* __restrict__ VTh, const u16* __restrict__ VTl,
    u16* __restrict__ SRh, u16* __restrict__ SRl) {
  const int lane = threadIdx.x;
  const int rr = lane & 15, kg = lane >> 4;
  const int b = blockIdx.z;
  const int row0 = blockIdx.y * 32, col0 = blockIdx.x * 48;
  const float* pa = ATTf + (size_t)(b * NN + row0 + rr) * NN + kg * 8;
  const u16* pbh = VTh + (size_t)b * 480 * 512 + (size_t)(col0 + rr) * 512 + kg * 8;
  const u16* pbl = VTl + (size_t)b * 480 * 512 + (size_t)(col0 + rr) * 512 + kg * 8;
  f32x4 acc[2][3] = {};
  float rs0 = 0.f, rs1 = 0.f;
  for (int k0 = 0; k0 < NN; k0 += 32) {
    bf16x8 a_h[2], a_l[2], b_h[3], b_l[3];
#pragma unroll
    for (int m = 0; m < 2; ++m) {
      float v[8];
      *(float4*)&v[0] = *(const float4*)(pa + (size_t)m * 16 * NN + k0);
      *(float4*)&v[4] = *(const float4*)(pa + (size_t)m * 16 * NN + k0 + 4);
      float part = 0.f;
#pragma unroll
      for (int j = 0; j < 8; ++j) { float e = __expf(v[j] * SCALEF); part += e; v[j] = e; }
      if (m == 0) rs0 += part; else rs1 += part;
      pack8(v, a_h[m], a_l[m]);
    }
#pragma unroll
    for (int f = 0; f < 3; ++f) {
      b_h[f] = *(const bf16x8*)(pbh + (size_t)f * 16 * 512 + k0);
      b_l[f] = *(const bf16x8*)(pbl + (size_t)f * 16 * 512 + k0);
    }
#pragma unroll
    for (int m = 0; m < 2; ++m)
#pragma unroll
      for (int f = 0; f < 3; ++f) { MFMA3(acc[m][f], (m ? a_h[1] : a_h[0]), (m ? a_l[1] : a_l[0]), b_h[f], b_l[f]) }
  }
  // full row sums: combine the 4 kg-lane partials, then broadcast to output rows
  rs0 += __shfl_xor(rs0, 16); rs0 += __shfl_xor(rs0, 32);
  rs1 += __shfl_xor(rs1, 16); rs1 += __shfl_xor(rs1, 32);
  const int rb = (lane >> 4) << 2, cc = lane & 15;
  float inv0[4], inv1[4];
#pragma unroll
  for (int r = 0; r < 4; ++r) {
    inv0[r] = 1.0f / __shfl(rs0, rb + r);
    inv1[r] = 1.0f / __shfl(rs1, rb + r);
  }
  u16* oh = SRh + (size_t)b * NN * 480;
  u16* ol = SRl + (size_t)b * NN * 480;
#pragma unroll
  for (int m = 0; m < 2; ++m)
#pragma unroll
    for (int f = 0; f < 3; ++f) {
      int n = col0 + f * 16 + cc;
#pragma unroll
      for (int r = 0; r < 4; ++r) {
        float v = acc[m][f][r] * (m ? inv1[r] : inv0[r]);
        u16 hi = f2bf(v);
        oh[(size_t)(row0 + m * 16 + rb + r) * 480 + n] = hi;
        ol[(size_t)(row0 + m * 16 + rb + r) * 480 + n] = f2bf(v - bf2f(hi));
      }
    }
}

// ---------------- k_outproj: SR @ [W_so|W_po]^T (f32 cols, live-K) + delta_xyz ----------------
__global__ __launch_bounds__(64) void k_outproj(
    const u16* __restrict__ SRh, const u16* __restrict__ SRl,
    const float* __restrict__ W_so, const float* __restrict__ b_so,
    const float* __restrict__ W_po, const float* __restrict__ b_po,
    u16* __restrict__ PRh, u16* __restrict__ PRl, float* __restrict__ out_xyz) {
  __shared__ float D[32][49];
  const int lane = threadIdx.x;
  const int rr = lane & 15, kg = lane >> 4;
  const int t = blockIdx.x;
  const int row0 = blockIdx.y * 32, col0 = t * 48;
  const float* W = (t < 8) ? W_so : W_po;
  const int kBeg = (t < 8) ? 0 : 192, kEnd = (t < 8) ? 192 : 480;
  const int wcol = (t < 8) ? col0 : col0 - 384;
  const u16* pah = SRh + (size_t)(row0 + rr) * 480 + kg * 8;
  const u16* pal = SRl + (size_t)(row0 + rr) * 480 + kg * 8;
  const float* pw = W + wcol + rr;
  f32x4 acc[2][3] = {};
  for (int k0 = kBeg; k0 < kEnd; k0 += 32) {
    bf16x8 a_h[2], a_l[2], b_h[3], b_l[3];
#pragma unroll
    for (int m = 0; m < 2; ++m) {
      a_h[m] = *(const bf16x8*)(pah + (size_t)m * 16 * 480 + k0);
      a_l[m] = *(const bf16x8*)(pal + (size_t)m * 16 * 480 + k0);
    }
    const float* bp0 = pw + (size_t)(k0 - kBeg + kg * 8) * 384;
#pragma unroll
    for (int f = 0; f < 3; ++f) {
      float v[8];
#pragma unroll
      for (int j = 0; j < 8; ++j) v[j] = bp0[(size_t)j * 384 + f * 16];
      pack8(v, b_h[f], b_l[f]);
    }
#pragma unroll
    for (int m = 0; m < 2; ++m)
#pragma unroll
      for (int f = 0; f < 3; ++f) { MFMA3(acc[m][f], a_h[m], a_l[m], b_h[f], b_l[f]) }
  }
  const int rb = (lane >> 4) << 2, cc = lane & 15;
#pragma unroll
  for (int m = 0; m < 2; ++m)
#pragma unroll
    for (int f = 0; f < 3; ++f) {
      int n = col0 + f * 16 + cc;
      float bias = (n < 384) ? b_so[n] : b_po[n - 384];
#pragma unroll
      for (int r = 0; r < 4; ++r) {
        float v = acc[m][f][r] + bias;
        u16 hi = f2bf(v);
        PRh[(size_t)(row0 + m * 16 + rb + r) * 768 + n] = hi;
        PRl[(size_t)(row0 + m * 16 + rb + r) * 768 + n] = f2bf(v - bf2f(hi));
        if (t >= 8) D[m * 16 + rb + r][f * 16 + cc] = v;
      }
    }
  if (t >= 8) {
    __syncthreads();
    if (lane < 32) {
      float sx = 0.f, sy = 0.f, sz = 0.f;
#pragma unroll
      for (int p = 0; p < 16; ++p) {
        sx += D[lane][3 * p];
        sy += D[lane][3 * p + 1];
        sz += D[lane][3 * p + 2];
      }
      int token = row0 + lane;
      atomicAdd(out_xyz + (size_t)token * 3 + 0, sx * (1.0f / 128.f));
      atomicAdd(out_xyz + (size_t)token * 3 + 1, sy * (1.0f / 128.f));
      atomicAdd(out_xyz + (size_t)token * 3 + 2, sz * (1.0f / 128.f));
    }
  }
}

// ---------------- k_final: PROJ @ W_fp^T (f32 cols), 2-wave K-split, LDS combine ----------------
__global__ __launch_bounds__(128) void k_final(
    const u16* __restrict__ PRh, const u16* __restrict__ PRl,
    const float* __restrict__ W_fp, const float* __restrict__ b_fp,
    float* __restrict__ out_res) {
  __shared__ float S[32][52];
  const int lane = threadIdx.x & 63;
  const int rr = lane & 15, kg = lane >> 4;
  const int wk = threadIdx.x >> 6;
  const int row0 = blockIdx.y * 32, col0 = blockIdx.x * 48;
  const int kBeg = wk * 384;
  const u16* pah = PRh + (size_t)(row0 + rr) * 768 + kg * 8;
  const u16* pal = PRl + (size_t)(row0 + rr) * 768 + kg * 8;
  const float* pw = W_fp + col0 + rr;
  f32x4 acc[2][3] = {};
  for (int k0 = kBeg; k0 < kBeg + 384; k0 += 32) {
    bf16x8 a_h[2], a_l[2], b_h[3], b_l[3];
#pragma unroll
    for (int m = 0; m < 2; ++m) {
      a_h[m] = *(const bf16x8*)(pah + (size_t)m * 16 * 768 + k0);
      a_l[m] = *(const bf16x8*)(pal + (size_t)m * 16 * 768 + k0);
    }
    const float* bp0 = pw + (size_t)(k0 + kg * 8) * 384;
#pragma unroll
    for (int f = 0; f < 3; ++f) {
      float v[8];
#pragma unroll
      for (int j = 0; j < 8; ++j) v[j] = bp0[(size_t)j * 384 + f * 16];
      pack8(v, b_h[f], b_l[f]);
    }
#pragma unroll
    for (int m = 0; m < 2; ++m)
#pragma unroll
      for (int f = 0; f < 3; ++f) { MFMA3(acc[m][f], a_h[m], a_l[m], b_h[f], b_l[f]) }
  }
  const int rb = (lane >> 4) << 2, cc = lane & 15;
  if (wk == 1) {
#pragma unroll
    for (int m = 0; m < 2; ++m)
#pragma unroll
      for (int f = 0; f < 3; ++f)
#pragma unroll
        for (int r = 0; r < 4; ++r)
          S[m * 16 + rb + r][f * 16 + cc] = acc[m][f][r];
  }
  __syncthreads();
  if (wk == 0) {
#pragma unroll
    for (int m = 0; m < 2; ++m)
#pragma unroll
      for (int f = 0; f < 3; ++f) {
        int n = col0 + f * 16 + cc;
#pragma unroll
        for (int r = 0; r < 4; ++r)
          out_res[(size_t)(row0 + m * 16 + rb + r) * 384 + n] =
              acc[m][f][r] + S[m * 16 + rb + r][f * 16 + cc] + b_fp[n];
      }
  }
}

extern "C" void kernel_launch(void* const* d_in, const int* in_sizes, int n_in,
                              void* d_out, int out_size, void* d_ws, size_t ws_size,
                              hipStream_t stream) {
  const float* hidden = (const float*)d_in[0];
  const float* xyz   = (const float*)d_in[1];
  const float* W_qk  = (const float*)d_in[2];
  const float* b_qk  = (const float*)d_in[3];
  const float* W_vs  = (const float*)d_in[4];
  const float* b_vs  = (const float*)d_in[5];
  const float* W_so  = (const float*)d_in[6];
  const float* b_so  = (const float*)d_in[7];
  const float* W_pqk = (const float*)d_in[8];
  const float* b_pqk = (const float*)d_in[9];
  const float* W_pv  = (const float*)d_in[10];
  const float* b_pv  = (const float*)d_in[11];
  const float* W_po  = (const float*)d_in[12];
  const float* b_po  = (const float*)d_in[13];
  const float* W_fp  = (const float*)d_in[14];
  const float* b_fp  = (const float*)d_in[15];

  float* out_res = (float*)d_out;                  // [B,N,384]
  float* out_xyz = out_res + (size_t)BB * NN * 384;

  u16* p   = (u16*)d_ws;
  u16* QKh = p;            p += 393216;   // 1024*384
  u16* QKl = p;            p += 393216;
  u16* VTh = p;            p += 491520;   // 2*480*512
  u16* VTl = p;            p += 491520;
  u16* SRh = p;            p += 491520;   // 1024*480
  u16* SRl = p;            p += 491520;
  u16* PRh = p;            p += 786432;   // 1024*768
  u16* PRl = p;            p += 786432;
  float* QPf  = (float*)p; p += 2 * 147456;  // 1024*144 f32
  float* ATTf = (float*)p;                   // 2*512*512 f32

  k_input<<<dim3(21, 32), 64, 0, stream>>>(hidden, xyz,
                                           W_qk, b_qk, W_vs, b_vs, W_pv, b_pv, W_pqk, b_pqk,
                                           QKh, QKl, VTh, VTl, QPf, out_xyz);
  k_attn<<<dim3(136, 1, 2), 256, 0, stream>>>(QKh, QKl, QPf, ATTf);
  k_pv<<<dim3(10, 16, 2), 64, 0, stream>>>(ATTf, VTh, VTl, SRh, SRl);
  k_outproj<<<dim3(16, 32), 64, 0, stream>>>(SRh, SRl, W_so, b_so, W_po, b_po,
                                             PRh, PRl, out_xyz);
  k_final<<<dim3(8, 32), 128, 0, stream>>>(PRh, PRl, W_fp, b_fp, out_res);
}

// Round 11
// 73.975 us; speedup vs baseline: 4.1406x; 1.3743x over previous
//
#include <hip/hip_runtime.h>
#include <math.h>

typedef unsigned short u16;
typedef __attribute__((ext_vector_type(8))) short bf16x8;
typedef __attribute__((ext_vector_type(4))) float f32x4;

#define BB 2
#define NN 512
#define SCALEF 0.17677669529663687f  // 1/sqrt(16 + 4*4)

__device__ __forceinline__ u16 f2bf(float x) {
  union { float f; unsigned u; } c; c.f = x;
  unsigned r = (c.u + 0x7FFFu + ((c.u >> 16) & 1u)) >> 16;
  return (u16)r;
}
__device__ __forceinline__ float bf2f(u16 h) {
  union { unsigned u; float f; } c; c.u = ((unsigned)h) << 16;
  return c.f;
}
__device__ __forceinline__ void pack8(const float* v, bf16x8& h, bf16x8& l) {
#pragma unroll
  for (int j = 0; j < 8; ++j) {
    u16 hi = f2bf(v[j]);
    h[j] = (short)hi;
    l[j] = (short)f2bf(v[j] - bf2f(hi));
  }
}
#define MFMA3(ACC, AH, AL, BH, BL)                                              \
  ACC = __builtin_amdgcn_mfma_f32_16x16x32_bf16(AH, BH, ACC, 0, 0, 0);          \
  ACC = __builtin_amdgcn_mfma_f32_16x16x32_bf16(AH, BL, ACC, 0, 0, 0);          \
  ACC = __builtin_amdgcn_mfma_f32_16x16x32_bf16(AL, BH, ACC, 0, 0, 0);

// ====== bf16 direct-global MFMA tile (used by k_attn QK) ======
template<int MR, int NF>
__device__ __forceinline__ void mfma_tile(
    const u16* __restrict__ Ah, const u16* __restrict__ Al, int lda,
    const u16* __restrict__ Bh, const u16* __restrict__ Bl, int ldb,
    int kBeg, int kEnd, int arow, int bcol, f32x4 (&acc)[MR][NF]) {
  const int lane = threadIdx.x & 63;
  const int rr = lane & 15, kg = lane >> 4;
  const u16* pah = Ah + (size_t)(arow + rr) * lda + kg * 8;
  const u16* pal = Al + (size_t)(arow + rr) * lda + kg * 8;
  const u16* pbh = Bh + (size_t)(bcol + rr) * ldb + kg * 8;
  const u16* pbl = Bl + (size_t)(bcol + rr) * ldb + kg * 8;
#pragma unroll 2
  for (int k0 = kBeg; k0 < kEnd; k0 += 32) {
    bf16x8 a_h[MR], a_l[MR], b_h[NF], b_l[NF];
#pragma unroll
    for (int m = 0; m < MR; ++m) {
      a_h[m] = *(const bf16x8*)(pah + (size_t)m * 16 * lda + k0);
      a_l[m] = *(const bf16x8*)(pal + (size_t)m * 16 * lda + k0);
    }
#pragma unroll
    for (int f = 0; f < NF; ++f) {
      b_h[f] = *(const bf16x8*)(pbh + (size_t)f * 16 * ldb + k0);
      b_l[f] = *(const bf16x8*)(pbl + (size_t)f * 16 * ldb + k0);
    }
#pragma unroll
    for (int m = 0; m < MR; ++m)
#pragma unroll
      for (int f = 0; f < NF; ++f) { MFMA3(acc[m][f], a_h[m], a_l[m], b_h[f], b_l[f]) }
  }
}

// ---------------- k_input: 4-wave K-split; hidden(f32) @ W^T(f32) -> QK | VT | QP ----------------
__global__ __launch_bounds__(256) void k_input(
    const float* __restrict__ hidden, const float* __restrict__ xyz,
    const float* __restrict__ W_qk, const float* __restrict__ b_qk,
    const float* __restrict__ W_vs, const float* __restrict__ b_vs,
    const float* __restrict__ W_pv, const float* __restrict__ b_pv,
    const float* __restrict__ W_pqk, const float* __restrict__ b_pqk,
    u16* __restrict__ QKh, u16* __restrict__ QKl,
    u16* __restrict__ VTh, u16* __restrict__ VTl,
    float* __restrict__ QPf, float* __restrict__ out_xyz) {
  __shared__ f32x4 CB[3][2][3][64];
  __shared__ u16 Dh[48][32], Dl[48][32];
  const int tid = threadIdx.x;
  const int w = tid >> 6, lane = tid & 63;
  const int rr = lane & 15, kg = lane >> 4;
  const int row0 = blockIdx.y * 32, col0 = blockIdx.x * 48;

  if (blockIdx.x == 18) {  // out_xyz init (once per 32-token slab)
    for (int t2 = tid; t2 < 96; t2 += 256)
      out_xyz[(size_t)row0 * 3 + t2] = xyz[(size_t)row0 * 3 + t2];
  }

  const float* W; const float* bias; int Ns, region;
  if (col0 < 384)      { W = W_qk;  Ns = 384; bias = b_qk + col0;          W += col0;       region = 0; }
  else if (col0 < 576) { W = W_vs;  Ns = 192; bias = b_vs + (col0 - 384);  W += col0 - 384; region = 1; }
  else if (col0 < 864) { W = W_pv;  Ns = 288; bias = b_pv + (col0 - 576);  W += col0 - 576; region = 1; }
  else                 { W = W_pqk; Ns = 144; bias = b_pqk + (col0 - 864); W += col0 - 864; region = 2; }

  f32x4 acc[2][3] = {};
  const float* pa = hidden + (size_t)(row0 + rr) * 384 + kg * 8;
  const float* pw = W + rr;
  for (int k0 = w * 32; k0 < 384; k0 += 128) {
    bf16x8 a_h[2], a_l[2], b_h[3], b_l[3];
#pragma unroll
    for (int m = 0; m < 2; ++m) {
      float v[8];
      *(float4*)&v[0] = *(const float4*)(pa + (size_t)m * 16 * 384 + k0);
      *(float4*)&v[4] = *(const float4*)(pa + (size_t)m * 16 * 384 + k0 + 4);
      pack8(v, a_h[m], a_l[m]);
    }
    const float* bp0 = pw + (size_t)(k0 + kg * 8) * Ns;
#pragma unroll
    for (int f = 0; f < 3; ++f) {
      float v[8];
#pragma unroll
      for (int j = 0; j < 8; ++j) v[j] = bp0[(size_t)j * Ns + f * 16];
      pack8(v, b_h[f], b_l[f]);
    }
#pragma unroll
    for (int m = 0; m < 2; ++m)
#pragma unroll
      for (int f = 0; f < 3; ++f) { MFMA3(acc[m][f], a_h[m], a_l[m], b_h[f], b_l[f]) }
  }
  if (w) {
#pragma unroll
    for (int m = 0; m < 2; ++m)
#pragma unroll
      for (int f = 0; f < 3; ++f) CB[w - 1][m][f][lane] = acc[m][f];
  }
  __syncthreads();
  if (w) return;
#pragma unroll
  for (int wv = 0; wv < 3; ++wv)
#pragma unroll
    for (int m = 0; m < 2; ++m)
#pragma unroll
      for (int f = 0; f < 3; ++f) acc[m][f] += CB[wv][m][f][lane];

  const int rb = (lane >> 4) << 2, cc = lane & 15;
  if (region == 0) {
#pragma unroll
    for (int f = 0; f < 3; ++f) {
      int n = col0 + f * 16 + cc;
      float bv = bias[f * 16 + cc];
#pragma unroll
      for (int m = 0; m < 2; ++m)
#pragma unroll
        for (int r = 0; r < 4; ++r) {
          float v = acc[m][f][r] + bv;
          int row = row0 + m * 16 + rb + r;
          u16 hi = f2bf(v);
          QKh[(size_t)row * 384 + n] = hi;
          QKl[(size_t)row * 384 + n] = f2bf(v - bf2f(hi));
        }
    }
  } else if (region == 2) {
#pragma unroll
    for (int f = 0; f < 3; ++f) {
      int c = (col0 - 864) + f * 16 + cc;
      float bv = bias[f * 16 + cc];
#pragma unroll
      for (int m = 0; m < 2; ++m)
#pragma unroll
        for (int r = 0; r < 4; ++r)
          QPf[(size_t)(row0 + m * 16 + rb + r) * 144 + c] = acc[m][f][r] + bv;
    }
  } else {
    // V region: transpose via LDS (single wave: same-wave LDS ordering is automatic)
#pragma unroll
    for (int f = 0; f < 3; ++f) {
      float bv = bias[f * 16 + cc];
#pragma unroll
      for (int m = 0; m < 2; ++m)
#pragma unroll
        for (int r = 0; r < 4; ++r) {
          float v = acc[m][f][r] + bv;
          u16 hi = f2bf(v);
          Dh[f * 16 + cc][m * 16 + rb + r] = hi;
          Dl[f * 16 + cc][m * 16 + rb + r] = f2bf(v - bf2f(hi));
        }
    }
    const int b = row0 >> 9, rl = row0 & 511;
    const int cbase = col0 - 384;
    u16* dsth = VTh + (size_t)b * 480 * 512;
    u16* dstl = VTl + (size_t)b * 480 * 512;
    for (int u = lane; u < 192; u += 64) {
      int c = u >> 2, seg = u & 3;
      *(uint4*)(dsth + (size_t)(cbase + c) * 512 + rl + seg * 8) = *(const uint4*)&Dh[c][seg * 8];
      *(uint4*)(dstl + (size_t)(cbase + c) * 512 + rl + seg * 8) = *(const uint4*)&Dl[c][seg * 8];
    }
  }
}

// ---------------- k_attn: fused point term + scalar QK, symmetric tiles (unchanged) ----------------
#define PROW 244
__global__ __launch_bounds__(256) void k_attn(
    const u16* __restrict__ QKh, const u16* __restrict__ QKl,
    const float* __restrict__ QPf, float* __restrict__ ATTf) {
  __shared__ float Pi[32][PROW];
  __shared__ float Pj[32][PROW];
  __shared__ float Sf[32 * 33];
  const int b = blockIdx.z;
  int t = blockIdx.x, ti_ = 0;
  while (t >= 16 - ti_) { t -= 16 - ti_; ++ti_; }
  const int tj_ = ti_ + t;
  const int i0 = ti_ * 32, j0 = tj_ * 32;
  const bool offdiag = (tj_ != ti_);
  const int tid = threadIdx.x;
  for (int u = tid; u < 3072; u += 256) {
    int side = (u >= 1536) ? 1 : 0;
    int rem = u - side * 1536;
    int row = rem / 48, hp = rem - row * 48;
    int grow = b * NN + (side ? j0 : i0) + row;
    const float* p = QPf + (size_t)grow * 144 + hp * 3;
    float x = p[0], y = p[1], z = p[2];
    float n2 = x * x + y * y + z * z;
    float inv = __frsqrt_rn(n2 + 1e-12f);
    float* dst = side ? &Pj[row][0] : &Pi[row][0];
    ((float4*)dst)[hp] = make_float4(x, y, z, n2);
    dst[192 + hp] = inv;
  }
  __syncthreads();
  const int tj = tid & 15, ti = tid >> 4;
  float a00 = 0.f, a01 = 0.f, a10 = 0.f, a11 = 0.f;
  {
    const float4* A0 = (const float4*)&Pi[ti][0];
    const float4* A1 = (const float4*)&Pi[ti + 16][0];
    const float4* B0 = (const float4*)&Pj[tj][0];
    const float4* B1 = (const float4*)&Pj[tj + 16][0];
    const float* iA0 = &Pi[ti][192];
    const float* iA1 = &Pi[ti + 16][192];
    const float* iB0 = &Pj[tj][192];
    const float* iB1 = &Pj[tj + 16][192];
#pragma unroll 4
    for (int hp = 0; hp < 48; ++hp) {
      float4 p0 = A0[hp], p1 = A1[hp], q0 = B0[hp], q1 = B1[hp];
      float va0 = iA0[hp], va1 = iA1[hp], vb0 = iB0[hp], vb1 = iB1[hp];
      {
        float dot = p0.x * q0.x + p0.y * q0.y + p0.z * q0.z;
        float d2 = fmaxf(fmaf(-2.f, dot, p0.w + q0.w), 0.f) + 1e-12f;
        a00 += d2 * __frsqrt_rn(d2) + dot * (va0 * vb0);
      }
      {
        float dot = p0.x * q1.x + p0.y * q1.y + p0.z * q1.z;
        float d2 = fmaxf(fmaf(-2.f, dot, p0.w + q1.w), 0.f) + 1e-12f;
        a01 += d2 * __frsqrt_rn(d2) + dot * (va0 * vb1);
      }
      {
        float dot = p1.x * q0.x + p1.y * q0.y + p1.z * q0.z;
        float d2 = fmaxf(fmaf(-2.f, dot, p1.w + q0.w), 0.f) + 1e-12f;
        a10 += d2 * __frsqrt_rn(d2) + dot * (va1 * vb0);
      }
      {
        float dot = p1.x * q1.x + p1.y * q1.y + p1.z * q1.z;
        float d2 = fmaxf(fmaf(-2.f, dot, p1.w + q1.w), 0.f) + 1e-12f;
        a11 += d2 * __frsqrt_rn(d2) + dot * (va1 * vb1);
      }
    }
  }
  Sf[ti * 33 + tj] = a00;
  Sf[ti * 33 + tj + 16] = a01;
  Sf[(ti + 16) * 33 + tj] = a10;
  Sf[(ti + 16) * 33 + tj + 16] = a11;
  f32x4 qij[1][1] = {}, qji[1][1] = {};
  const int w = tid >> 6, lane = tid & 63;
  {
    int arow = b * NN + i0 + (w >> 1) * 16;
    int brow = b * NN + j0 + (w & 1) * 16;
    mfma_tile<1, 1>(QKh, QKl, 384, QKh + 192, QKl + 192, 384, 0, 192, arow, brow, qij);
    if (offdiag) {
      int arow2 = b * NN + j0 + (w >> 1) * 16;
      int brow2 = b * NN + i0 + (w & 1) * 16;
      mfma_tile<1, 1>(QKh, QKl, 384, QKh + 192, QKl + 192, 384, 0, 192, arow2, brow2, qji);
    }
  }
  __syncthreads();
  const int rl = (w >> 1) * 16 + ((lane >> 4) << 2);
  const int cl = (w & 1) * 16 + (lane & 15);
  float* Cb = ATTf + (size_t)b * NN * NN;
#pragma unroll
  for (int r = 0; r < 4; ++r)
    Cb[(size_t)(i0 + rl + r) * NN + j0 + cl] = qij[0][0][r] + Sf[(rl + r) * 33 + cl];
  if (offdiag) {
#pragma unroll
    for (int r = 0; r < 4; ++r)
      Cb[(size_t)(j0 + rl + r) * NN + i0 + cl] = qji[0][0][r] + Sf[cl * 33 + rl + r];
  }
}

// ---------------- k_pv: 4-wave K-split; exp-in-register, deferred normalization ----------------
__global__ __launch_bounds__(256) void k_pv(
    const float* __restrict__ ATTf,
    const u16* __restrict__ VTh, const u16* __restrict__ VTl,
    u16* __restrict__ SRh, u16* __restrict__ SRl) {
  __shared__ f32x4 CB[3][2][3][64];
  __shared__ float RS[3][2][64];
  const int tid = threadIdx.x;
  const int w = tid >> 6, lane = tid & 63;
  const int rr = lane & 15, kg = lane >> 4;
  const int b = blockIdx.z;
  const int row0 = blockIdx.y * 32, col0 = blockIdx.x * 48;
  const float* pa = ATTf + (size_t)(b * NN + row0 + rr) * NN + kg * 8;
  const u16* pbh = VTh + (size_t)b * 480 * 512 + (size_t)(col0 + rr) * 512 + kg * 8;
  const u16* pbl = VTl + (size_t)b * 480 * 512 + (size_t)(col0 + rr) * 512 + kg * 8;
  f32x4 acc[2][3] = {};
  float rs0 = 0.f, rs1 = 0.f;
  for (int k0 = w * 32; k0 < NN; k0 += 128) {
    bf16x8 a_h[2], a_l[2], b_h[3], b_l[3];
#pragma unroll
    for (int m = 0; m < 2; ++m) {
      float v[8];
      *(float4*)&v[0] = *(const float4*)(pa + (size_t)m * 16 * NN + k0);
      *(float4*)&v[4] = *(const float4*)(pa + (size_t)m * 16 * NN + k0 + 4);
      float part = 0.f;
#pragma unroll
      for (int j = 0; j < 8; ++j) { float e = __expf(v[j] * SCALEF); part += e; v[j] = e; }
      if (m == 0) rs0 += part; else rs1 += part;
      pack8(v, a_h[m], a_l[m]);
    }
#pragma unroll
    for (int f = 0; f < 3; ++f) {
      b_h[f] = *(const bf16x8*)(pbh + (size_t)f * 16 * 512 + k0);
      b_l[f] = *(const bf16x8*)(pbl + (size_t)f * 16 * 512 + k0);
    }
#pragma unroll
    for (int m = 0; m < 2; ++m)
#pragma unroll
      for (int f = 0; f < 3; ++f) { MFMA3(acc[m][f], (m ? a_h[1] : a_h[0]), (m ? a_l[1] : a_l[0]), b_h[f], b_l[f]) }
  }
  if (w) {
#pragma unroll
    for (int m = 0; m < 2; ++m)
#pragma unroll
      for (int f = 0; f < 3; ++f) CB[w - 1][m][f][lane] = acc[m][f];
    RS[w - 1][0][lane] = rs0;
    RS[w - 1][1][lane] = rs1;
  }
  __syncthreads();
  if (w) return;
#pragma unroll
  for (int wv = 0; wv < 3; ++wv) {
#pragma unroll
    for (int m = 0; m < 2; ++m)
#pragma unroll
      for (int f = 0; f < 3; ++f) acc[m][f] += CB[wv][m][f][lane];
    rs0 += RS[wv][0][lane];
    rs1 += RS[wv][1][lane];
  }
  rs0 += __shfl_xor(rs0, 16); rs0 += __shfl_xor(rs0, 32);
  rs1 += __shfl_xor(rs1, 16); rs1 += __shfl_xor(rs1, 32);
  const int rb = (lane >> 4) << 2, cc = lane & 15;
  float inv0[4], inv1[4];
#pragma unroll
  for (int r = 0; r < 4; ++r) {
    inv0[r] = 1.0f / __shfl(rs0, rb + r);
    inv1[r] = 1.0f / __shfl(rs1, rb + r);
  }
  u16* oh = SRh + (size_t)b * NN * 480;
  u16* ol = SRl + (size_t)b * NN * 480;
#pragma unroll
  for (int m = 0; m < 2; ++m)
#pragma unroll
    for (int f = 0; f < 3; ++f) {
      int n = col0 + f * 16 + cc;
#pragma unroll
      for (int r = 0; r < 4; ++r) {
        float v = acc[m][f][r] * (m ? inv1[r] : inv0[r]);
        u16 hi = f2bf(v);
        oh[(size_t)(row0 + m * 16 + rb + r) * 480 + n] = hi;
        ol[(size_t)(row0 + m * 16 + rb + r) * 480 + n] = f2bf(v - bf2f(hi));
      }
    }
}

// ---------------- k_outproj: 4-wave K-split, live-K only, + delta_xyz ----------------
__global__ __launch_bounds__(256) void k_outproj(
    const u16* __restrict__ SRh, const u16* __restrict__ SRl,
    const float* __restrict__ W_so, const float* __restrict__ b_so,
    const float* __restrict__ W_po, const float* __restrict__ b_po,
    u16* __restrict__ PRh, u16* __restrict__ PRl, float* __restrict__ out_xyz) {
  __shared__ f32x4 CB[3][2][3][64];
  __shared__ float D[32][49];
  const int tid = threadIdx.x;
  const int w = tid >> 6, lane = tid & 63;
  const int rr = lane & 15, kg = lane >> 4;
  const int t = blockIdx.x;
  const int row0 = blockIdx.y * 32, col0 = t * 48;
  const float* W = (t < 8) ? W_so : W_po;
  const int kBeg = (t < 8) ? 0 : 192, kEnd = (t < 8) ? 192 : 480;
  const int wcol = (t < 8) ? col0 : col0 - 384;
  const u16* pah = SRh + (size_t)(row0 + rr) * 480 + kg * 8;
  const u16* pal = SRl + (size_t)(row0 + rr) * 480 + kg * 8;
  const float* pw = W + wcol + rr;
  f32x4 acc[2][3] = {};
  for (int k0 = kBeg + w * 32; k0 < kEnd; k0 += 128) {
    bf16x8 a_h[2], a_l[2], b_h[3], b_l[3];
#pragma unroll
    for (int m = 0; m < 2; ++m) {
      a_h[m] = *(const bf16x8*)(pah + (size_t)m * 16 * 480 + k0);
      a_l[m] = *(const bf16x8*)(pal + (size_t)m * 16 * 480 + k0);
    }
    const float* bp0 = pw + (size_t)(k0 - kBeg + kg * 8) * 384;
#pragma unroll
    for (int f = 0; f < 3; ++f) {
      float v[8];
#pragma unroll
      for (int j = 0; j < 8; ++j) v[j] = bp0[(size_t)j * 384 + f * 16];
      pack8(v, b_h[f], b_l[f]);
    }
#pragma unroll
    for (int m = 0; m < 2; ++m)
#pragma unroll
      for (int f = 0; f < 3; ++f) { MFMA3(acc[m][f], a_h[m], a_l[m], b_h[f], b_l[f]) }
  }
  if (w) {
#pragma unroll
    for (int m = 0; m < 2; ++m)
#pragma unroll
      for (int f = 0; f < 3; ++f) CB[w - 1][m][f][lane] = acc[m][f];
  }
  __syncthreads();
  if (w) return;
#pragma unroll
  for (int wv = 0; wv < 3; ++wv)
#pragma unroll
    for (int m = 0; m < 2; ++m)
#pragma unroll
      for (int f = 0; f < 3; ++f) acc[m][f] += CB[wv][m][f][lane];
  const int rb = (lane >> 4) << 2, cc = lane & 15;
#pragma unroll
  for (int m = 0; m < 2; ++m)
#pragma unroll
    for (int f = 0; f < 3; ++f) {
      int n = col0 + f * 16 + cc;
      float bias = (n < 384) ? b_so[n] : b_po[n - 384];
#pragma unroll
      for (int r = 0; r < 4; ++r) {
        float v = acc[m][f][r] + bias;
        u16 hi = f2bf(v);
        PRh[(size_t)(row0 + m * 16 + rb + r) * 768 + n] = hi;
        PRl[(size_t)(row0 + m * 16 + rb + r) * 768 + n] = f2bf(v - bf2f(hi));
        if (t >= 8) D[m * 16 + rb + r][f * 16 + cc] = v;
      }
    }
  if (t >= 8) {
    if (lane < 32) {
      float sx = 0.f, sy = 0.f, sz = 0.f;
#pragma unroll
      for (int p = 0; p < 16; ++p) {
        sx += D[lane][3 * p];
        sy += D[lane][3 * p + 1];
        sz += D[lane][3 * p + 2];
      }
      int token = row0 + lane;
      atomicAdd(out_xyz + (size_t)token * 3 + 0, sx * (1.0f / 128.f));
      atomicAdd(out_xyz + (size_t)token * 3 + 1, sy * (1.0f / 128.f));
      atomicAdd(out_xyz + (size_t)token * 3 + 2, sz * (1.0f / 128.f));
    }
  }
}

// ---------------- k_final: 4-wave K-split over K=768 ----------------
__global__ __launch_bounds__(256) void k_final(
    const u16* __restrict__ PRh, const u16* __restrict__ PRl,
    const float* __restrict__ W_fp, const float* __restrict__ b_fp,
    float* __restrict__ out_res) {
  __shared__ f32x4 CB[3][2][3][64];
  const int tid = threadIdx.x;
  const int w = tid >> 6, lane = tid & 63;
  const int rr = lane & 15, kg = lane >> 4;
  const int row0 = blockIdx.y * 32, col0 = blockIdx.x * 48;
  const u16* pah = PRh + (size_t)(row0 + rr) * 768 + kg * 8;
  const u16* pal = PRl + (size_t)(row0 + rr) * 768 + kg * 8;
  const float* pw = W_fp + col0 + rr;
  f32x4 acc[2][3] = {};
  for (int k0 = w * 32; k0 < 768; k0 += 128) {
    bf16x8 a_h[2], a_l[2], b_h[3], b_l[3];
#pragma unroll
    for (int m = 0; m < 2; ++m) {
      a_h[m] = *(const bf16x8*)(pah + (size_t)m * 16 * 768 + k0);
      a_l[m] = *(const bf16x8*)(pal + (size_t)m * 16 * 768 + k0);
    }
    const float* bp0 = pw + (size_t)(k0 + kg * 8) * 384;
#pragma unroll
    for (int f = 0; f < 3; ++f) {
      float v[8];
#pragma unroll
      for (int j = 0; j < 8; ++j) v[j] = bp0[(size_t)j * 384 + f * 16];
      pack8(v, b_h[f], b_l[f]);
    }
#pragma unroll
    for (int m = 0; m < 2; ++m)
#pragma unroll
      for (int f = 0; f < 3; ++f) { MFMA3(acc[m][f], a_h[m], a_l[m], b_h[f], b_l[f]) }
  }
  if (w) {
#pragma unroll
    for (int m = 0; m < 2; ++m)
#pragma unroll
      for (int f = 0; f < 3; ++f) CB[w - 1][m][f][lane] = acc[m][f];
  }
  __syncthreads();
  if (w) return;
#pragma unroll
  for (int wv = 0; wv < 3; ++wv)
#pragma unroll
    for (int m = 0; m < 2; ++m)
#pragma unroll
      for (int f = 0; f < 3; ++f) acc[m][f] += CB[wv][m][f][lane];
  const int rb = (lane >> 4) << 2, cc = lane & 15;
#pragma unroll
  for (int m = 0; m < 2; ++m)
#pragma unroll
    for (int f = 0; f < 3; ++f) {
      int n = col0 + f * 16 + cc;
#pragma unroll
      for (int r = 0; r < 4; ++r)
        out_res[(size_t)(row0 + m * 16 + rb + r) * 384 + n] = acc[m][f][r] + b_fp[n];
    }
}

extern "C" void kernel_launch(void* const* d_in, const int* in_sizes, int n_in,
                              void* d_out, int out_size, void* d_ws, size_t ws_size,
                              hipStream_t stream) {
  const float* hidden = (const float*)d_in[0];
  const float* xyz   = (const float*)d_in[1];
  const float* W_qk  = (const float*)d_in[2];
  const float* b_qk  = (const float*)d_in[3];
  const float* W_vs  = (const float*)d_in[4];
  const float* b_vs  = (const float*)d_in[5];
  const float* W_so  = (const float*)d_in[6];
  const float* b_so  = (const float*)d_in[7];
  const float* W_pqk = (const float*)d_in[8];
  const float* b_pqk = (const float*)d_in[9];
  const float* W_pv  = (const float*)d_in[10];
  const float* b_pv  = (const float*)d_in[11];
  const float* W_po  = (const float*)d_in[12];
  const float* b_po  = (const float*)d_in[13];
  const float* W_fp  = (const float*)d_in[14];
  const float* b_fp  = (const float*)d_in[15];

  float* out_res = (float*)d_out;                  // [B,N,384]
  float* out_xyz = out_res + (size_t)BB * NN * 384;

  u16* p   = (u16*)d_ws;
  u16* QKh = p;            p += 393216;   // 1024*384
  u16* QKl = p;            p += 393216;
  u16* VTh = p;            p += 491520;   // 2*480*512
  u16* VTl = p;            p += 491520;
  u16* SRh = p;            p += 491520;   // 1024*480
  u16* SRl = p;            p += 491520;
  u16* PRh = p;            p += 786432;   // 1024*768
  u16* PRl = p;            p += 786432;
  float* QPf  = (float*)p; p += 2 * 147456;  // 1024*144 f32
  float* ATTf = (float*)p;                   // 2*512*512 f32

  k_input<<<dim3(21, 32), 256, 0, stream>>>(hidden, xyz,
                                            W_qk, b_qk, W_vs, b_vs, W_pv, b_pv, W_pqk, b_pqk,
                                            QKh, QKl, VTh, VTl, QPf, out_xyz);
  k_attn<<<dim3(136, 1, 2), 256, 0, stream>>>(QKh, QKl, QPf, ATTf);
  k_pv<<<dim3(10, 16, 2), 256, 0, stream>>>(ATTf, VTh, VTl, SRh, SRl);
  k_outproj<<<dim3(16, 32), 256, 0, stream>>>(SRh, SRl, W_so, b_so, W_po, b_po,
                                              PRh, PRl, out_xyz);
  k_final<<<dim3(8, 32), 256, 0, stream>>>(PRh, PRl, W_fp, b_fp, out_res);
}

// Round 12
// 71.027 us; speedup vs baseline: 4.3125x; 1.0415x over previous
//
#include <hip/hip_runtime.h>
#include <math.h>

typedef unsigned short u16;
typedef __attribute__((ext_vector_type(8))) short bf16x8;
typedef __attribute__((ext_vector_type(4))) float f32x4;

#define BB 2
#define NN 512
#define SCALEF 0.17677669529663687f  // 1/sqrt(16 + 4*4)

__device__ __forceinline__ u16 f2bf(float x) {
  union { float f; unsigned u; } c; c.f = x;
  unsigned r = (c.u + 0x7FFFu + ((c.u >> 16) & 1u)) >> 16;
  return (u16)r;
}
__device__ __forceinline__ float bf2f(u16 h) {
  union { unsigned u; float f; } c; c.u = ((unsigned)h) << 16;
  return c.f;
}
__device__ __forceinline__ void pack8(const float* v, bf16x8& h, bf16x8& l) {
#pragma unroll
  for (int j = 0; j < 8; ++j) {
    u16 hi = f2bf(v[j]);
    h[j] = (short)hi;
    l[j] = (short)f2bf(v[j] - bf2f(hi));
  }
}
#define MFMA3(ACC, AH, AL, BH, BL)                                              \
  ACC = __builtin_amdgcn_mfma_f32_16x16x32_bf16(AH, BH, ACC, 0, 0, 0);          \
  ACC = __builtin_amdgcn_mfma_f32_16x16x32_bf16(AH, BL, ACC, 0, 0, 0);          \
  ACC = __builtin_amdgcn_mfma_f32_16x16x32_bf16(AL, BH, ACC, 0, 0, 0);

// ====== bf16 direct-global MFMA tile (used by k_attn QK) ======
template<int MR, int NF>
__device__ __forceinline__ void mfma_tile(
    const u16* __restrict__ Ah, const u16* __restrict__ Al, int lda,
    const u16* __restrict__ Bh, const u16* __restrict__ Bl, int ldb,
    int kBeg, int kEnd, int arow, int bcol, f32x4 (&acc)[MR][NF]) {
  const int lane = threadIdx.x & 63;
  const int rr = lane & 15, kg = lane >> 4;
  const u16* pah = Ah + (size_t)(arow + rr) * lda + kg * 8;
  const u16* pal = Al + (size_t)(arow + rr) * lda + kg * 8;
  const u16* pbh = Bh + (size_t)(bcol + rr) * ldb + kg * 8;
  const u16* pbl = Bl + (size_t)(bcol + rr) * ldb + kg * 8;
#pragma unroll 2
  for (int k0 = kBeg; k0 < kEnd; k0 += 32) {
    bf16x8 a_h[MR], a_l[MR], b_h[NF], b_l[NF];
#pragma unroll
    for (int m = 0; m < MR; ++m) {
      a_h[m] = *(const bf16x8*)(pah + (size_t)m * 16 * lda + k0);
      a_l[m] = *(const bf16x8*)(pal + (size_t)m * 16 * lda + k0);
    }
#pragma unroll
    for (int f = 0; f < NF; ++f) {
      b_h[f] = *(const bf16x8*)(pbh + (size_t)f * 16 * ldb + k0);
      b_l[f] = *(const bf16x8*)(pbl + (size_t)f * 16 * ldb + k0);
    }
#pragma unroll
    for (int m = 0; m < MR; ++m)
#pragma unroll
      for (int f = 0; f < NF; ++f) { MFMA3(acc[m][f], a_h[m], a_l[m], b_h[f], b_l[f]) }
  }
}

// ---------------- k_input: 8-wave K-split; hidden(f32) @ W^T(f32) -> QK | VT | QP ----------------
__global__ __launch_bounds__(512) void k_input(
    const float* __restrict__ hidden, const float* __restrict__ xyz,
    const float* __restrict__ W_qk, const float* __restrict__ b_qk,
    const float* __restrict__ W_vs, const float* __restrict__ b_vs,
    const float* __restrict__ W_pv, const float* __restrict__ b_pv,
    const float* __restrict__ W_pqk, const float* __restrict__ b_pqk,
    u16* __restrict__ QKh, u16* __restrict__ QKl,
    u16* __restrict__ VTh, u16* __restrict__ VTl,
    float* __restrict__ QPf, float* __restrict__ out_xyz) {
  __shared__ f32x4 CB[7][2][3][64];
  __shared__ u16 Dh[48][32], Dl[48][32];
  const int tid = threadIdx.x;
  const int w = tid >> 6, lane = tid & 63;
  const int rr = lane & 15, kg = lane >> 4;
  const int row0 = blockIdx.y * 32, col0 = blockIdx.x * 48;

  if (blockIdx.x == 18) {
    for (int t2 = tid; t2 < 96; t2 += 512)
      out_xyz[(size_t)row0 * 3 + t2] = xyz[(size_t)row0 * 3 + t2];
  }

  const float* W; const float* bias; int Ns, region;
  if (col0 < 384)      { W = W_qk;  Ns = 384; bias = b_qk + col0;          W += col0;       region = 0; }
  else if (col0 < 576) { W = W_vs;  Ns = 192; bias = b_vs + (col0 - 384);  W += col0 - 384; region = 1; }
  else if (col0 < 864) { W = W_pv;  Ns = 288; bias = b_pv + (col0 - 576);  W += col0 - 576; region = 1; }
  else                 { W = W_pqk; Ns = 144; bias = b_pqk + (col0 - 864); W += col0 - 864; region = 2; }

  f32x4 acc[2][3] = {};
  const float* pa = hidden + (size_t)(row0 + rr) * 384 + kg * 8;
  const float* pw = W + rr;
  for (int k0 = w * 32; k0 < 384; k0 += 256) {
    bf16x8 a_h[2], a_l[2], b_h[3], b_l[3];
#pragma unroll
    for (int m = 0; m < 2; ++m) {
      float v[8];
      *(float4*)&v[0] = *(const float4*)(pa + (size_t)m * 16 * 384 + k0);
      *(float4*)&v[4] = *(const float4*)(pa + (size_t)m * 16 * 384 + k0 + 4);
      pack8(v, a_h[m], a_l[m]);
    }
    const float* bp0 = pw + (size_t)(k0 + kg * 8) * Ns;
#pragma unroll
    for (int f = 0; f < 3; ++f) {
      float v[8];
#pragma unroll
      for (int j = 0; j < 8; ++j) v[j] = bp0[(size_t)j * Ns + f * 16];
      pack8(v, b_h[f], b_l[f]);
    }
#pragma unroll
    for (int m = 0; m < 2; ++m)
#pragma unroll
      for (int f = 0; f < 3; ++f) { MFMA3(acc[m][f], a_h[m], a_l[m], b_h[f], b_l[f]) }
  }
  if (w) {
#pragma unroll
    for (int m = 0; m < 2; ++m)
#pragma unroll
      for (int f = 0; f < 3; ++f) CB[w - 1][m][f][lane] = acc[m][f];
  }
  __syncthreads();
  if (w) return;
#pragma unroll
  for (int wv = 0; wv < 7; ++wv)
#pragma unroll
    for (int m = 0; m < 2; ++m)
#pragma unroll
      for (int f = 0; f < 3; ++f) acc[m][f] += CB[wv][m][f][lane];

  const int rb = (lane >> 4) << 2, cc = lane & 15;
  if (region == 0) {
#pragma unroll
    for (int f = 0; f < 3; ++f) {
      int n = col0 + f * 16 + cc;
      float bv = bias[f * 16 + cc];
#pragma unroll
      for (int m = 0; m < 2; ++m)
#pragma unroll
        for (int r = 0; r < 4; ++r) {
          float v = acc[m][f][r] + bv;
          int row = row0 + m * 16 + rb + r;
          u16 hi = f2bf(v);
          QKh[(size_t)row * 384 + n] = hi;
          QKl[(size_t)row * 384 + n] = f2bf(v - bf2f(hi));
        }
    }
  } else if (region == 2) {
#pragma unroll
    for (int f = 0; f < 3; ++f) {
      int c = (col0 - 864) + f * 16 + cc;
      float bv = bias[f * 16 + cc];
#pragma unroll
      for (int m = 0; m < 2; ++m)
#pragma unroll
        for (int r = 0; r < 4; ++r)
          QPf[(size_t)(row0 + m * 16 + rb + r) * 144 + c] = acc[m][f][r] + bv;
    }
  } else {
    // V region: transpose via LDS (single wave: same-wave LDS ordering)
#pragma unroll
    for (int f = 0; f < 3; ++f) {
      float bv = bias[f * 16 + cc];
#pragma unroll
      for (int m = 0; m < 2; ++m)
#pragma unroll
        for (int r = 0; r < 4; ++r) {
          float v = acc[m][f][r] + bv;
          u16 hi = f2bf(v);
          Dh[f * 16 + cc][m * 16 + rb + r] = hi;
          Dl[f * 16 + cc][m * 16 + rb + r] = f2bf(v - bf2f(hi));
        }
    }
    const int b = row0 >> 9, rl = row0 & 511;
    const int cbase = col0 - 384;
    u16* dsth = VTh + (size_t)b * 480 * 512;
    u16* dstl = VTl + (size_t)b * 480 * 512;
    for (int u = lane; u < 192; u += 64) {
      int c = u >> 2, seg = u & 3;
      *(uint4*)(dsth + (size_t)(cbase + c) * 512 + rl + seg * 8) = *(const uint4*)&Dh[c][seg * 8];
      *(uint4*)(dstl + (size_t)(cbase + c) * 512 + rl + seg * 8) = *(const uint4*)&Dl[c][seg * 8];
    }
  }
}

// ---------------- k_attn: 512 threads; hp-split point term + dir-split QK ----------------
#define PROW 244
__global__ __launch_bounds__(512) void k_attn(
    const u16* __restrict__ QKh, const u16* __restrict__ QKl,
    const float* __restrict__ QPf, float* __restrict__ ATTf) {
  __shared__ float Pi[32][PROW];
  __shared__ float Pj[32][PROW];
  __shared__ float Sf[2][32 * 33];
  const int b = blockIdx.z;
  int t = blockIdx.x, ti_ = 0;
  while (t >= 16 - ti_) { t -= 16 - ti_; ++ti_; }
  const int tj_ = ti_ + t;
  const int i0 = ti_ * 32, j0 = tj_ * 32;
  const bool offdiag = (tj_ != ti_);
  const int tid = threadIdx.x;
  for (int u = tid; u < 3072; u += 512) {
    int side = (u >= 1536) ? 1 : 0;
    int rem = u - side * 1536;
    int row = rem / 48, hp = rem - row * 48;
    int grow = b * NN + (side ? j0 : i0) + row;
    const float* p = QPf + (size_t)grow * 144 + hp * 3;
    float x = p[0], y = p[1], z = p[2];
    float n2 = x * x + y * y + z * z;
    float inv = __frsqrt_rn(n2 + 1e-12f);
    float* dst = side ? &Pj[row][0] : &Pi[row][0];
    ((float4*)dst)[hp] = make_float4(x, y, z, n2);
    dst[192 + hp] = inv;
  }
  __syncthreads();
  // point term: thread group h covers hp in [24h, 24h+24)
  const int h = tid >> 8;
  const int t8 = tid & 255;
  const int tj = t8 & 15, ti = t8 >> 4;
  {
    float a00 = 0.f, a01 = 0.f, a10 = 0.f, a11 = 0.f;
    const float4* A0 = (const float4*)&Pi[ti][0];
    const float4* A1 = (const float4*)&Pi[ti + 16][0];
    const float4* B0 = (const float4*)&Pj[tj][0];
    const float4* B1 = (const float4*)&Pj[tj + 16][0];
    const float* iA0 = &Pi[ti][192];
    const float* iA1 = &Pi[ti + 16][192];
    const float* iB0 = &Pj[tj][192];
    const float* iB1 = &Pj[tj + 16][192];
    const int hpB = h * 24, hpE = hpB + 24;
#pragma unroll 4
    for (int hp = hpB; hp < hpE; ++hp) {
      float4 p0 = A0[hp], p1 = A1[hp], q0 = B0[hp], q1 = B1[hp];
      float va0 = iA0[hp], va1 = iA1[hp], vb0 = iB0[hp], vb1 = iB1[hp];
      {
        float dot = p0.x * q0.x + p0.y * q0.y + p0.z * q0.z;
        float d2 = fmaxf(fmaf(-2.f, dot, p0.w + q0.w), 0.f) + 1e-12f;
        a00 += d2 * __frsqrt_rn(d2) + dot * (va0 * vb0);
      }
      {
        float dot = p0.x * q1.x + p0.y * q1.y + p0.z * q1.z;
        float d2 = fmaxf(fmaf(-2.f, dot, p0.w + q1.w), 0.f) + 1e-12f;
        a01 += d2 * __frsqrt_rn(d2) + dot * (va0 * vb1);
      }
      {
        float dot = p1.x * q0.x + p1.y * q0.y + p1.z * q0.z;
        float d2 = fmaxf(fmaf(-2.f, dot, p1.w + q0.w), 0.f) + 1e-12f;
        a10 += d2 * __frsqrt_rn(d2) + dot * (va1 * vb0);
      }
      {
        float dot = p1.x * q1.x + p1.y * q1.y + p1.z * q1.z;
        float d2 = fmaxf(fmaf(-2.f, dot, p1.w + q1.w), 0.f) + 1e-12f;
        a11 += d2 * __frsqrt_rn(d2) + dot * (va1 * vb1);
      }
    }
    Sf[h][ti * 33 + tj] = a00;
    Sf[h][ti * 33 + tj + 16] = a01;
    Sf[h][(ti + 16) * 33 + tj] = a10;
    Sf[h][(ti + 16) * 33 + tj + 16] = a11;
  }
  // scalar QK: waves 0-3 compute (i,j); waves 4-7 compute (j,i) when offdiag
  const int w = tid >> 6, lane = tid & 63;
  const int dir = w >> 2, sub = w & 3;
  f32x4 q[1][1] = {};
  if (dir == 0) {
    int arow = b * NN + i0 + (sub >> 1) * 16;
    int brow = b * NN + j0 + (sub & 1) * 16;
    mfma_tile<1, 1>(QKh, QKl, 384, QKh + 192, QKl + 192, 384, 0, 192, arow, brow, q);
  } else if (offdiag) {
    int arow = b * NN + j0 + (sub >> 1) * 16;
    int brow = b * NN + i0 + (sub & 1) * 16;
    mfma_tile<1, 1>(QKh, QKl, 384, QKh + 192, QKl + 192, 384, 0, 192, arow, brow, q);
  }
  __syncthreads();
  const int rl = (sub >> 1) * 16 + ((lane >> 4) << 2);
  const int cl = (sub & 1) * 16 + (lane & 15);
  float* Cb = ATTf + (size_t)b * NN * NN;
  if (dir == 0) {
#pragma unroll
    for (int r = 0; r < 4; ++r)
      Cb[(size_t)(i0 + rl + r) * NN + j0 + cl] =
          q[0][0][r] + Sf[0][(rl + r) * 33 + cl] + Sf[1][(rl + r) * 33 + cl];
  } else if (offdiag) {
#pragma unroll
    for (int r = 0; r < 4; ++r)
      Cb[(size_t)(j0 + rl + r) * NN + i0 + cl] =
          q[0][0][r] + Sf[0][cl * 33 + rl + r] + Sf[1][cl * 33 + rl + r];
  }
}

// ---------------- k_pv: 8-wave K-split, MR=1; exp-in-register, deferred normalization ----------------
__global__ __launch_bounds__(512) void k_pv(
    const float* __restrict__ ATTf,
    const u16* __restrict__ VTh, const u16* __restrict__ VTl,
    u16* __restrict__ SRh, u16* __restrict__ SRl) {
  __shared__ f32x4 CB[7][3][64];
  __shared__ float RS[7][64];
  const int tid = threadIdx.x;
  const int w = tid >> 6, lane = tid & 63;
  const int rr = lane & 15, kg = lane >> 4;
  const int b = blockIdx.z;
  const int row0 = blockIdx.y * 16, col0 = blockIdx.x * 48;
  const float* pa = ATTf + (size_t)(b * NN + row0 + rr) * NN + kg * 8;
  const u16* pbh = VTh + (size_t)b * 480 * 512 + (size_t)(col0 + rr) * 512 + kg * 8;
  const u16* pbl = VTl + (size_t)b * 480 * 512 + (size_t)(col0 + rr) * 512 + kg * 8;
  f32x4 acc[3] = {};
  float rs = 0.f;
  for (int k0 = w * 32; k0 < NN; k0 += 256) {
    bf16x8 a_h, a_l, b_h[3], b_l[3];
    {
      float v[8];
      *(float4*)&v[0] = *(const float4*)(pa + k0);
      *(float4*)&v[4] = *(const float4*)(pa + k0 + 4);
#pragma unroll
      for (int j = 0; j < 8; ++j) { float e = __expf(v[j] * SCALEF); rs += e; v[j] = e; }
      pack8(v, a_h, a_l);
    }
#pragma unroll
    for (int f = 0; f < 3; ++f) {
      b_h[f] = *(const bf16x8*)(pbh + (size_t)f * 16 * 512 + k0);
      b_l[f] = *(const bf16x8*)(pbl + (size_t)f * 16 * 512 + k0);
    }
#pragma unroll
    for (int f = 0; f < 3; ++f) { MFMA3(acc[f], a_h, a_l, b_h[f], b_l[f]) }
  }
  if (w) {
#pragma unroll
    for (int f = 0; f < 3; ++f) CB[w - 1][f][lane] = acc[f];
    RS[w - 1][lane] = rs;
  }
  __syncthreads();
  if (w) return;
#pragma unroll
  for (int wv = 0; wv < 7; ++wv) {
#pragma unroll
    for (int f = 0; f < 3; ++f) acc[f] += CB[wv][f][lane];
    rs += RS[wv][lane];
  }
  rs += __shfl_xor(rs, 16);
  rs += __shfl_xor(rs, 32);
  const int rb = (lane >> 4) << 2, cc = lane & 15;
  float inv[4];
#pragma unroll
  for (int r = 0; r < 4; ++r) inv[r] = 1.0f / __shfl(rs, rb + r);
  u16* oh = SRh + (size_t)b * NN * 480;
  u16* ol = SRl + (size_t)b * NN * 480;
#pragma unroll
  for (int f = 0; f < 3; ++f) {
    int n = col0 + f * 16 + cc;
#pragma unroll
    for (int r = 0; r < 4; ++r) {
      float v = acc[f][r] * inv[r];
      u16 hi = f2bf(v);
      oh[(size_t)(row0 + rb + r) * 480 + n] = hi;
      ol[(size_t)(row0 + rb + r) * 480 + n] = f2bf(v - bf2f(hi));
    }
  }
}

// ---------------- k_outproj: 8-wave K-split, MR=1, live-K only, + delta_xyz ----------------
__global__ __launch_bounds__(512) void k_outproj(
    const u16* __restrict__ SRh, const u16* __restrict__ SRl,
    const float* __restrict__ W_so, const float* __restrict__ b_so,
    const float* __restrict__ W_po, const float* __restrict__ b_po,
    u16* __restrict__ PRh, u16* __restrict__ PRl, float* __restrict__ out_xyz) {
  __shared__ f32x4 CB[7][3][64];
  __shared__ float D[16][49];
  const int tid = threadIdx.x;
  const int w = tid >> 6, lane = tid & 63;
  const int rr = lane & 15, kg = lane >> 4;
  const int t = blockIdx.x;
  const int row0 = blockIdx.y * 16, col0 = t * 48;
  const float* W = (t < 8) ? W_so : W_po;
  const int kBeg = (t < 8) ? 0 : 192, kEnd = (t < 8) ? 192 : 480;
  const int wcol = (t < 8) ? col0 : col0 - 384;
  const u16* pah = SRh + (size_t)(row0 + rr) * 480 + kg * 8;
  const u16* pal = SRl + (size_t)(row0 + rr) * 480 + kg * 8;
  const float* pw = W + wcol + rr;
  f32x4 acc[3] = {};
  for (int k0 = kBeg + w * 32; k0 < kEnd; k0 += 256) {
    bf16x8 a_h, a_l, b_h[3], b_l[3];
    a_h = *(const bf16x8*)(pah + k0);
    a_l = *(const bf16x8*)(pal + k0);
    const float* bp0 = pw + (size_t)(k0 - kBeg + kg * 8) * 384;
#pragma unroll
    for (int f = 0; f < 3; ++f) {
      float v[8];
#pragma unroll
      for (int j = 0; j < 8; ++j) v[j] = bp0[(size_t)j * 384 + f * 16];
      pack8(v, b_h[f], b_l[f]);
    }
#pragma unroll
    for (int f = 0; f < 3; ++f) { MFMA3(acc[f], a_h, a_l, b_h[f], b_l[f]) }
  }
  if (w) {
#pragma unroll
    for (int f = 0; f < 3; ++f) CB[w - 1][f][lane] = acc[f];
  }
  __syncthreads();
  if (w) return;
#pragma unroll
  for (int wv = 0; wv < 7; ++wv)
#pragma unroll
    for (int f = 0; f < 3; ++f) acc[f] += CB[wv][f][lane];
  const int rb = (lane >> 4) << 2, cc = lane & 15;
#pragma unroll
  for (int f = 0; f < 3; ++f) {
    int n = col0 + f * 16 + cc;
    float bias = (n < 384) ? b_so[n] : b_po[n - 384];
#pragma unroll
    for (int r = 0; r < 4; ++r) {
      float v = acc[f][r] + bias;
      u16 hi = f2bf(v);
      PRh[(size_t)(row0 + rb + r) * 768 + n] = hi;
      PRl[(size_t)(row0 + rb + r) * 768 + n] = f2bf(v - bf2f(hi));
      if (t >= 8) D[rb + r][f * 16 + cc] = v;
    }
  }
  if (t >= 8 && lane < 16) {
    float sx = 0.f, sy = 0.f, sz = 0.f;
#pragma unroll
    for (int p = 0; p < 16; ++p) {
      sx += D[lane][3 * p];
      sy += D[lane][3 * p + 1];
      sz += D[lane][3 * p + 2];
    }
    int token = row0 + lane;
    atomicAdd(out_xyz + (size_t)token * 3 + 0, sx * (1.0f / 128.f));
    atomicAdd(out_xyz + (size_t)token * 3 + 1, sy * (1.0f / 128.f));
    atomicAdd(out_xyz + (size_t)token * 3 + 2, sz * (1.0f / 128.f));
  }
}

// ---------------- k_final: 8-wave K-split, MR=1, K=768 ----------------
__global__ __launch_bounds__(512) void k_final(
    const u16* __restrict__ PRh, const u16* __restrict__ PRl,
    const float* __restrict__ W_fp, const float* __restrict__ b_fp,
    float* __restrict__ out_res) {
  __shared__ f32x4 CB[7][3][64];
  const int tid = threadIdx.x;
  const int w = tid >> 6, lane = tid & 63;
  const int rr = lane & 15, kg = lane >> 4;
  const int row0 = blockIdx.y * 16, col0 = blockIdx.x * 48;
  const u16* pah = PRh + (size_t)(row0 + rr) * 768 + kg * 8;
  const u16* pal = PRl + (size_t)(row0 + rr) * 768 + kg * 8;
  const float* pw = W_fp + col0 + rr;
  f32x4 acc[3] = {};
  for (int k0 = w * 32; k0 < 768; k0 += 256) {
    bf16x8 a_h, a_l, b_h[3], b_l[3];
    a_h = *(const bf16x8*)(pah + k0);
    a_l = *(const bf16x8*)(pal + k0);
    const float* bp0 = pw + (size_t)(k0 + kg * 8) * 384;
#pragma unroll
    for (int f = 0; f < 3; ++f) {
      float v[8];
#pragma unroll
      for (int j = 0; j < 8; ++j) v[j] = bp0[(size_t)j * 384 + f * 16];
      pack8(v, b_h[f], b_l[f]);
    }
#pragma unroll
    for (int f = 0; f < 3; ++f) { MFMA3(acc[f], a_h, a_l, b_h[f], b_l[f]) }
  }
  if (w) {
#pragma unroll
    for (int f = 0; f < 3; ++f) CB[w - 1][f][lane] = acc[f];
  }
  __syncthreads();
  if (w) return;
#pragma unroll
  for (int wv = 0; wv < 7; ++wv)
#pragma unroll
    for (int f = 0; f < 3; ++f) acc[f] += CB[wv][f][lane];
  const int rb = (lane >> 4) << 2, cc = lane & 15;
#pragma unroll
  for (int f = 0; f < 3; ++f) {
    int n = col0 + f * 16 + cc;
#pragma unroll
    for (int r = 0; r < 4; ++r)
      out_res[(size_t)(row0 + rb + r) * 384 + n] = acc[f][r] + b_fp[n];
  }
}

extern "C" void kernel_launch(void* const* d_in, const int* in_sizes, int n_in,
                              void* d_out, int out_size, void* d_ws, size_t ws_size,
                              hipStream_t stream) {
  const float* hidden = (const float*)d_in[0];
  const float* xyz   = (const float*)d_in[1];
  const float* W_qk  = (const float*)d_in[2];
  const float* b_qk  = (const float*)d_in[3];
  const float* W_vs  = (const float*)d_in[4];
  const float* b_vs  = (const float*)d_in[5];
  const float* W_so  = (const float*)d_in[6];
  const float* b_so  = (const float*)d_in[7];
  const float* W_pqk = (const float*)d_in[8];
  const float* b_pqk = (const float*)d_in[9];
  const float* W_pv  = (const float*)d_in[10];
  const float* b_pv  = (const float*)d_in[11];
  const float* W_po  = (const float*)d_in[12];
  const float* b_po  = (const float*)d_in[13];
  const float* W_fp  = (const float*)d_in[14];
  const float* b_fp  = (const float*)d_in[15];

  float* out_res = (float*)d_out;                  // [B,N,384]
  float* out_xyz = out_res + (size_t)BB * NN * 384;

  u16* p   = (u16*)d_ws;
  u16* QKh = p;            p += 393216;   // 1024*384
  u16* QKl = p;            p += 393216;
  u16* VTh = p;            p += 491520;   // 2*480*512
  u16* VTl = p;            p += 491520;
  u16* SRh = p;            p += 491520;   // 1024*480
  u16* SRl = p;            p += 491520;
  u16* PRh = p;            p += 786432;   // 1024*768
  u16* PRl = p;            p += 786432;
  float* QPf  = (float*)p; p += 2 * 147456;  // 1024*144 f32
  float* ATTf = (float*)p;                   // 2*512*512 f32

  k_input<<<dim3(21, 32), 512, 0, stream>>>(hidden, xyz,
                                            W_qk, b_qk, W_vs, b_vs, W_pv, b_pv, W_pqk, b_pqk,
                                            QKh, QKl, VTh, VTl, QPf, out_xyz);
  k_attn<<<dim3(136, 1, 2), 512, 0, stream>>>(QKh, QKl, QPf, ATTf);
  k_pv<<<dim3(10, 32, 2), 512, 0, stream>>>(ATTf, VTh, VTl, SRh, SRl);
  k_outproj<<<dim3(16, 64), 512, 0, stream>>>(SRh, SRl, W_so, b_so, W_po, b_po,
                                              PRh, PRl, out_xyz);
  k_final<<<dim3(8, 64), 512, 0, stream>>>(PRh, PRl, W_fp, b_fp, out_res);
}